// Round 12
// baseline (633.743 us; speedup 1.0000x reference)
//
#include <hip/hip_runtime.h>
#include <hip/hip_bf16.h>
#include <math.h>

// GETS calibrator: MoE-GCN. N nodes, E edges, C=64, F=512, FH=32, DH=16.
// R12: k_final launched as 64-thread blocks (grid=ceil(n/64)) -- R11 ran 391
//      blocks of 256 => 1.5 blocks/CU => 17.8% occupancy; the uniform scalar-W
//      stream needs many co-resident waves to amortize K$ line fills.

#define XD 160   // aggregated feature dim (Zt layout)
#define CC 64    // classes
#define NREP 4   // counter replicas

typedef __attribute__((ext_vector_type(8))) short short8;
typedef __attribute__((ext_vector_type(4))) float f32x4;

static __device__ inline unsigned pk_bf16(float a, float b) {
  __hip_bfloat162 h;
  h.x = __float2bfloat16(a);
  h.y = __float2bfloat16(b);
  return *reinterpret_cast<unsigned*>(&h);
}
static __device__ inline unsigned short bf16u(float f) {
  __hip_bfloat16 h = __float2bfloat16(f);
  return *reinterpret_cast<unsigned short*>(&h);
}
static __device__ inline float bf_lo(unsigned u) {
  unsigned v = u << 16;
  return __builtin_bit_cast(float, v);
}
static __device__ inline float bf_hi(unsigned u) {
  unsigned v = u & 0xffff0000u;
  return __builtin_bit_cast(float, v);
}

// ---------------- degree counting: packed (outdeg<<16 | indeg), 4 replicas ----------------
__global__ void k_degrees(const int* __restrict__ ei, int E,
                          unsigned* __restrict__ cntP, int n) {
  int e = blockIdx.x * blockDim.x + threadIdx.x;
  if (e >= E) return;
  int s = ei[e], d = ei[E + e];
  unsigned r = threadIdx.x & (NREP - 1);
  atomicAdd(&cntP[r * (size_t)n + d], 1u);        // indeg
  atomicAdd(&cntP[r * (size_t)n + s], 0x10000u);  // outdeg
}

// ---------------- 2-level exclusive scan of indeg -> row_start ----------------
__global__ void k_scan1(const unsigned* __restrict__ cntP, int n, int* __restrict__ bsum) {
  __shared__ int red[1024];
  int tid = threadIdx.x;
  int i = blockIdx.x * 1024 + tid;
  int v = 0;
  if (i < n) {
    unsigned t = 0;
#pragma unroll
    for (int r = 0; r < NREP; ++r) t += cntP[r * (size_t)n + i];
    v = (int)(t & 0xFFFFu);
  }
  red[tid] = v;
  __syncthreads();
  for (int s = 512; s > 0; s >>= 1) {
    if (tid < s) red[tid] += red[tid + s];
    __syncthreads();
  }
  if (tid == 0) bsum[blockIdx.x] = red[0];
}

__global__ void k_scan2(int* __restrict__ bsum, int nb, int* __restrict__ row_start, int n) {
  if (threadIdx.x == 0 && blockIdx.x == 0) {
    int run = 0;
    for (int b = 0; b < nb; ++b) { int t = bsum[b]; bsum[b] = run; run += t; }
    row_start[n] = run;   // == E
  }
}

__global__ void k_scan3(const unsigned* __restrict__ cntP, int n, const int* __restrict__ bsum,
                        int* __restrict__ row_start, float* __restrict__ dinv,
                        int* __restrict__ deg_i) {
  __shared__ int sc[1024];
  int tid = threadIdx.x;
  int i = blockIdx.x * 1024 + tid;
  int indeg = 0, total = 0;
  if (i < n) {
    unsigned t = 0;
#pragma unroll
    for (int r = 0; r < NREP; ++r) t += cntP[r * (size_t)n + i];
    indeg = (int)(t & 0xFFFFu);
    total = indeg + (int)(t >> 16);
  }
  sc[tid] = indeg;
  __syncthreads();
  for (int ofs = 1; ofs < 1024; ofs <<= 1) {
    int t = (tid >= ofs) ? sc[tid - ofs] : 0;
    __syncthreads();
    sc[tid] += t;
    __syncthreads();
  }
  if (i < n) {
    int incl = sc[tid];
    row_start[i] = incl - indeg + bsum[blockIdx.x];
    dinv[i] = rsqrtf((float)indeg + 1.0f);   // GCN deg = indeg + 1 (self loop)
    deg_i[i] = total;                        // embedding degree = indeg + outdeg
  }
}

// ---------------- CSR fill: (src | deg<<20, coef) per edge ----------------
__global__ void k_fill(const int* __restrict__ ei, int E, const int* __restrict__ row_start,
                       int* __restrict__ cursor, const float* __restrict__ dinv,
                       const int* __restrict__ deg_i, int2* __restrict__ ec) {
  int e = blockIdx.x * blockDim.x + threadIdx.x;
  if (e >= E) return;
  int s = ei[e], d = ei[E + e];
  int pos = row_start[d] + atomicAdd(&cursor[d], 1);
  int dg = deg_i[s]; if (dg > 127) dg = 127;
  int2 v;
  v.x = s | (dg << 20);
  v.y = __float_as_int(dinv[s] * dinv[d]);
  ec[pos] = v;
}

// ---------------- Wv = Wfg(512x32) @ wg[64:96] (3 cols), fp32 ----------------
__global__ void k_wv(const float* __restrict__ Wfg, const float* __restrict__ bfg,
                     const float* __restrict__ wg, float* __restrict__ Wv4) {
  int k = blockIdx.x * blockDim.x + threadIdx.x;
  if (k >= 512) return;
  float a0 = 0.f, a1 = 0.f, a2 = 0.f;
  for (int j = 0; j < 32; ++j) {
    float w = Wfg[k * 32 + j];
    a0 += w * wg[(64 + j) * 3 + 0];
    a1 += w * wg[(64 + j) * 3 + 1];
    a2 += w * wg[(64 + j) * 3 + 2];
  }
  float4 v; v.x = a0; v.y = a1; v.z = a2; v.w = 0.f;
  *(float4*)&Wv4[k * 4] = v;
  if (k == 0) {
    float c0 = 0.f, c1 = 0.f, c2 = 0.f;
    for (int j = 0; j < 32; ++j) {
      float b = bfg[j];
      c0 += b * wg[(64 + j) * 3 + 0];
      c1 += b * wg[(64 + j) * 3 + 1];
      c2 += b * wg[(64 + j) * 3 + 2];
    }
    float4 c; c.x = c0; c.y = c1; c.z = c2; c.w = 0.f;
    *(float4*)&Wv4[512 * 4] = c;
  }
}

// ---------------- k_projm: bf16 MFMA  feat(n,512) @ [Wf0|Wf2](512,64) + fp32 CFG -------
// Xu row 64 uints (256B): [logits pairs u0..31 | f0 u32..47 | f2 u48..63]
__global__ __launch_bounds__(256) void k_projm(
    const float* __restrict__ feat,
    const float* __restrict__ Wf0, const float* __restrict__ bf0,
    const float* __restrict__ Wf2, const float* __restrict__ bf2,
    const float* __restrict__ Wv4,
    unsigned* __restrict__ Xu, float* __restrict__ CFG, int n) {
  __shared__ unsigned short Al[2][64][40];    // [buf][node][k 0..31 bf16], 80B row (16B pad)
  __shared__ unsigned short Bs[2][4][64][8];  // [buf][ntile][lane][j] frag-ordered

  int t = threadIdx.x;
  int l = t & 63;
  int w = t >> 6;
  int blk = blockIdx.x;

  int node_s = t >> 2;            // 0..63
  int kq = t & 3;                 // k-quarter within the 32-wide K-step
  int gn_s = blk * 64 + node_s;
  int gn_c = gn_s < n ? gn_s : n - 1;
  const float* frow = feat + (size_t)gn_c * 512 + kq * 8;

  int bk = (l >> 4) * 8;                    // k_local base
  int bc = (w << 4) + (l & 15);             // col 0..63
  const float* wsrc = (bc < 32) ? (Wf0 + bc) : (Wf2 + (bc - 32));

  float cfg0 = 0.f, cfg1 = 0.f, cfg2 = 0.f;

  auto stage = [&](int ks, int buf) {
    float4 fa = *(const float4*)&frow[ks * 32];
    float4 fb = *(const float4*)&frow[ks * 32 + 4];
    float fv[8] = {fa.x, fa.y, fa.z, fa.w, fb.x, fb.y, fb.z, fb.w};
    const float* wv = Wv4 + (ks * 32 + kq * 8) * 4;
#pragma unroll
    for (int j = 0; j < 8; ++j) {
      float4 v = *(const float4*)&wv[j * 4];
      cfg0 += fv[j] * v.x;
      cfg1 += fv[j] * v.y;
      cfg2 += fv[j] * v.z;
    }
    unsigned short pa[8];
#pragma unroll
    for (int j = 0; j < 8; ++j) pa[j] = bf16u(fv[j]);
    *(uint4*)&Al[buf][node_s][kq * 8] = *(const uint4*)pa;
    unsigned short pb[8];
#pragma unroll
    for (int j = 0; j < 8; ++j)
      pb[j] = bf16u(wsrc[(size_t)(ks * 32 + bk + j) * 32]);
    *(uint4*)&Bs[buf][w][l][0] = *(const uint4*)pb;
  };

  f32x4 acc[4];
#pragma unroll
  for (int q = 0; q < 4; ++q) acc[q] = (f32x4){0.f, 0.f, 0.f, 0.f};

  stage(0, 0);
  int cur = 0;
  for (int ks = 0; ks < 16; ++ks) {
    __syncthreads();
    if (ks < 15) stage(ks + 1, cur ^ 1);
    short8 af = *(const short8*)&Al[cur][(w << 4) + (l & 15)][(l >> 4) * 8];
#pragma unroll
    for (int nt = 0; nt < 4; ++nt) {
      short8 bfv = *(const short8*)&Bs[cur][nt][l][0];
      acc[nt] = __builtin_amdgcn_mfma_f32_16x16x32_bf16(af, bfv, acc[nt], 0, 0, 0);
    }
    cur ^= 1;
  }

  cfg0 += __shfl_xor(cfg0, 1); cfg0 += __shfl_xor(cfg0, 2);
  cfg1 += __shfl_xor(cfg1, 1); cfg1 += __shfl_xor(cfg1, 2);
  cfg2 += __shfl_xor(cfg2, 1); cfg2 += __shfl_xor(cfg2, 2);
  if (kq == 0 && gn_s < n) {
    float4 cc = *(const float4*)&Wv4[512 * 4];
    CFG[gn_s] = cfg0 + cc.x;
    CFG[n + gn_s] = cfg1 + cc.y;
    CFG[2 * (size_t)n + gn_s] = cfg2 + cc.z;
  }

  // ---- store X (bf16): D[row=(l>>4)*4+r][col=nt*16+(l&15)]; feature = 64+col ----
  unsigned short* Xus = (unsigned short*)Xu;
#pragma unroll
  for (int nt = 0; nt < 4; ++nt) {
    int col = (nt << 4) + (l & 15);
    float bias = (col < 32) ? bf0[col] : bf2[col - 32];
    int fidx = 64 + col;   // f0 -> 64..95, f2 -> 96..127 (compact layout)
#pragma unroll
    for (int r = 0; r < 4; ++r) {
      int nd = blk * 64 + (w << 4) + ((l >> 4) << 2) + r;
      if (nd < n) Xus[(size_t)nd * 128 + fidx] = bf16u(acc[nt][r] + bias);
    }
  }
}

// ---------------- build X (bf16): logits pairs ----------------
__global__ void k_buildx(const float* __restrict__ logits,
                         unsigned* __restrict__ Xu, int n) {
  int gid = blockIdx.x * blockDim.x + threadIdx.x;
  if (gid >= n * 32) return;
  int node = gid >> 5, p = gid & 31;
  const float* lgr = logits + (size_t)node * 64;
  float2 lg = *(const float2*)&lgr[2 * p];
  Xu[(size_t)node * 64 + p] = pk_bf16(lg.x, lg.y);
}

// ---------------- aggregation: Zt(bf16) = A_hat @ [Xu(256B rows) | Emb(packed deg)] ------
__global__ __launch_bounds__(256) void k_agg(
    const unsigned* __restrict__ Xu, unsigned* __restrict__ Ztu,
    const int* __restrict__ row_start, const int2* __restrict__ ec,
    const int* __restrict__ deg_i,
    const float* __restrict__ Emb1, const float* __restrict__ Emb2,
    const float* __restrict__ dinv, int n) {
  int w = threadIdx.x >> 6, l = threadIdx.x & 63;
  int node = blockIdx.x * 4 + w;
  if (node >= n) return;
  int beg = row_start[node], end = row_start[node + 1];

  const float* etab = (l < 8) ? (Emb1 + 2 * l) : (Emb2 + 2 * (l - 8));

  float ax = 0.f, ay = 0.f, bx = 0.f, by = 0.f;
  int i = beg;
  for (; i + 2 <= end; i += 2) {
    int2 e0 = ec[i];
    int2 e1 = ec[i + 1];
    int s0 = e0.x & 0xFFFFF;
    int s1 = e1.x & 0xFFFFF;
    float c0 = __int_as_float(e0.y);
    float c1 = __int_as_float(e1.y);
    unsigned u0 = Xu[(size_t)s0 * 64 + l];
    unsigned u1 = Xu[(size_t)s1 * 64 + l];
    ax += c0 * bf_lo(u0); ay += c0 * bf_hi(u0);
    ax += c1 * bf_lo(u1); ay += c1 * bf_hi(u1);
    if (l < 16) {
      float2 ev0 = *(const float2*)&etab[(e0.x >> 20) * 16];
      float2 ev1 = *(const float2*)&etab[(e1.x >> 20) * 16];
      bx += c0 * ev0.x; by += c0 * ev0.y;
      bx += c1 * ev1.x; by += c1 * ev1.y;
    }
  }
  if (i < end) {
    int2 e0 = ec[i];
    int s0 = e0.x & 0xFFFFF;
    float c0 = __int_as_float(e0.y);
    unsigned u0 = Xu[(size_t)s0 * 64 + l];
    ax += c0 * bf_lo(u0); ay += c0 * bf_hi(u0);
    if (l < 16) {
      float2 ev0 = *(const float2*)&etab[(e0.x >> 20) * 16];
      bx += c0 * ev0.x; by += c0 * ev0.y;
    }
  }
  // self loop
  float di = dinv[node];
  float c2 = di * di;
  {
    unsigned u = Xu[(size_t)node * 64 + l];
    ax += c2 * bf_lo(u);
    ay += c2 * bf_hi(u);
    if (l < 16) {
      int dg = deg_i[node]; if (dg > 127) dg = 127;
      float2 ev = *(const float2*)&etab[dg * 16];
      bx += c2 * ev.x;
      by += c2 * ev.y;
    }
  }
  // main store: new feature nf=2l -> old feature (nf<96 ? nf : nf+16)
  {
    int nf = 2 * l;
    int of = nf + (nf >= 96 ? 16 : 0);
    Ztu[2 * ((size_t)(of >> 2) * n + node) + ((of >> 1) & 1)] = pk_bf16(ax, ay);
  }
  if (l < 16) {
    int p = l & 7;
    int of = (l < 8) ? (96 + 2 * p) : (144 + 2 * p);
    Ztu[2 * ((size_t)(of >> 2) * n + node) + (p & 1)] = pk_bf16(bx, by);
  }
}

// ---------------- final: 1 wave per block (occupancy), lane=node, scalar W ----------------
__global__ __launch_bounds__(64) void k_final(
    const unsigned* __restrict__ Ztu, const float* __restrict__ logits,
    const float* __restrict__ CFG, const int* __restrict__ deg_i,
    const float* __restrict__ W0, const float* __restrict__ b0,
    const float* __restrict__ W1, const float* __restrict__ b1,
    const float* __restrict__ W2, const float* __restrict__ b2,
    const float* __restrict__ Embg, const float* __restrict__ wg,
    float* __restrict__ out, int n) {
  int l = threadIdx.x;
  int g = blockIdx.x;
  int node = g * 64 + l;
  int nc = node < n ? node : n - 1;

  // ---- gating (fp32): logits part + Embg part + folded FG part ----
  float c0 = 0.f, c1 = 0.f, c2 = 0.f;
  const float* lgr = logits + (size_t)nc * 64;
#pragma unroll
  for (int q = 0; q < 16; ++q) {
    float4 v = *(const float4*)&lgr[q * 4];
    const float* p = (const float*)&v;
#pragma unroll
    for (int j = 0; j < 4; ++j) {
      int k = q * 4 + j;
      c0 += p[j] * wg[k * 3 + 0];
      c1 += p[j] * wg[k * 3 + 1];
      c2 += p[j] * wg[k * 3 + 2];
    }
  }
  {
    int dg = deg_i[nc]; if (dg > 127) dg = 127;
    const float* egr = Embg + dg * 16;
#pragma unroll
    for (int q = 0; q < 4; ++q) {
      float4 v = *(const float4*)&egr[q * 4];
      const float* p = (const float*)&v;
#pragma unroll
      for (int j = 0; j < 4; ++j) {
        int k = 96 + q * 4 + j;
        c0 += p[j] * wg[k * 3 + 0];
        c1 += p[j] * wg[k * 3 + 1];
        c2 += p[j] * wg[k * 3 + 2];
      }
    }
  }
  c0 += CFG[nc];
  c1 += CFG[n + nc];
  c2 += CFG[2 * (size_t)n + nc];

  int i0 = 0; float t0 = c0;
  if (c1 > t0) { t0 = c1; i0 = 1; }
  if (c2 > t0) { t0 = c2; i0 = 2; }
  float t1 = -3.4e38f; int i1 = 0;
  if (i0 != 0) { t1 = c0; i1 = 0; }
  if (i0 != 1 && c1 > t1) { t1 = c1; i1 = 1; }
  if (i0 != 2 && c2 > t1) { t1 = c2; i1 = 2; }
  float e1v = expf(t1 - t0);
  float gsum = 1.0f + e1v;
  float gA = 1.0f / gsum, gB = e1v / gsum;
  float g0 = (i0 == 0) ? gA : (i1 == 0) ? gB : 0.f;
  float g1 = (i0 == 1) ? gA : (i1 == 1) ? gB : 0.f;
  float g2 = (i0 == 2) ? gA : (i1 == 2) ? gB : 0.f;

  float comb[64];
#pragma unroll
  for (int c = 0; c < 64; ++c) comb[c] = 0.f;

#define CHUNK(CIDX, GE, WPTR, KROW)                                        \
  {                                                                        \
    uint2 zu = *(const uint2*)&Ztu[2 * ((size_t)(CIDX) * n + nc)];         \
    float zs[4] = {(GE) * bf_lo(zu.x), (GE) * bf_hi(zu.x),                 \
                   (GE) * bf_lo(zu.y), (GE) * bf_hi(zu.y)};                \
    const float* wr = (WPTR) + (KROW) * 64;                                \
    _Pragma("unroll") for (int kk = 0; kk < 4; ++kk) {                     \
      float zz = zs[kk];                                                   \
      const float* wrow = wr + kk * 64;                                    \
      _Pragma("unroll") for (int c = 0; c < 64; ++c)                       \
        comb[c] += zz * wrow[c];                                           \
    }                                                                      \
  }

  for (int t = 0; t < 24; ++t) CHUNK(t, g0, W0, 4 * t);
  for (int t = 0; t < 16; ++t) CHUNK(t, g1, W1, 4 * t);
  for (int t = 0; t < 4; ++t)  CHUNK(24 + t, g1, W1, 64 + 4 * t);
  for (int t = 0; t < 12; ++t) CHUNK(28 + t, g2, W2, 4 * t);
#undef CHUNK

#pragma unroll
  for (int c = 0; c < 64; ++c)
    comb[c] += g0 * b0[c] + g1 * b1[c] + g2 * b2[c];

  if (node < n) {
    float4* outr = (float4*)(out + (size_t)node * 64);
#pragma unroll
    for (int q = 0; q < 16; ++q) {
      float4 lg4 = *(const float4*)&lgr[q * 4];
      const float* pl = (const float*)&lg4;
      float4 o;
      float* po = (float*)&o;
#pragma unroll
      for (int j = 0; j < 4; ++j) {
        float v = comb[q * 4 + j];
        float sp = fmaxf(v, 0.f) + log1pf(expf(-fabsf(v)));
        po[j] = pl[j] * sp;
      }
      outr[q] = o;
    }
  }
}

extern "C" void kernel_launch(void* const* d_in, const int* in_sizes, int n_in,
                              void* d_out, int out_size, void* d_ws, size_t ws_size,
                              hipStream_t stream) {
  const float* logits = (const float*)d_in[0];
  const float* feat   = (const float*)d_in[1];
  const int*   ei     = (const int*)d_in[2];
  const float* Wf0 = (const float*)d_in[3];
  const float* bf0 = (const float*)d_in[4];
  const float* W0  = (const float*)d_in[5];
  const float* b0  = (const float*)d_in[6];
  const float* Emb1= (const float*)d_in[7];
  const float* W1  = (const float*)d_in[8];
  const float* b1  = (const float*)d_in[9];
  const float* Wf2 = (const float*)d_in[10];
  const float* bf2 = (const float*)d_in[11];
  const float* Emb2= (const float*)d_in[12];
  const float* W2  = (const float*)d_in[13];
  const float* b2  = (const float*)d_in[14];
  const float* Wfg = (const float*)d_in[15];
  const float* bfg = (const float*)d_in[16];
  const float* Embg= (const float*)d_in[17];
  const float* wg  = (const float*)d_in[18];

  int n = in_sizes[0] / 64;
  int E = in_sizes[2] / 2;

  char* base = (char*)d_ws;
  size_t off = 0;
  auto alloc = [&](size_t bytes) -> void* {
    void* p = base + off;
    off += bytes;
    off = (off + 255) & ~(size_t)255;
    return p;
  };
  unsigned* cntP   = (unsigned*)alloc((size_t)NREP * n * 4);
  int*   cursor    = (int*)alloc((size_t)n * 4);
  size_t zero_bytes = off;                 // cntP + cursor
  int*   deg_i     = (int*)alloc((size_t)n * 4);
  int*   row_start = (int*)alloc(((size_t)n + 1) * 4);
  int*   bsum      = (int*)alloc(1024 * 4);
  float* dinv      = (float*)alloc((size_t)n * 4);
  int2*  ec        = (int2*)alloc((size_t)E * 8);
  float* CFG       = (float*)alloc((size_t)n * 3 * 4);
  float* Wv4       = (float*)alloc((size_t)513 * 4 * 4);
  unsigned* Xu     = (unsigned*)alloc((size_t)n * 64 * 4);   // bf16 X: 128 feat x 2B
  unsigned* Ztu    = (unsigned*)alloc((size_t)n * 80 * 4);   // bf16 Zt (160 feat)
  (void)ws_size;

  hipMemsetAsync(base, 0, zero_bytes, stream);

  int nb_scan = (n + 1023) / 1024;
  k_degrees<<<(E + 255) / 256, 256, 0, stream>>>(ei, E, cntP, n);
  k_scan1<<<nb_scan, 1024, 0, stream>>>(cntP, n, bsum);
  k_scan2<<<1, 64, 0, stream>>>(bsum, nb_scan, row_start, n);
  k_scan3<<<nb_scan, 1024, 0, stream>>>(cntP, n, bsum, row_start, dinv, deg_i);
  k_wv<<<2, 256, 0, stream>>>(Wfg, bfg, wg, Wv4);
  k_projm<<<(n + 63) / 64, 256, 0, stream>>>(feat, Wf0, bf0, Wf2, bf2, Wv4, Xu, CFG, n);
  k_buildx<<<((size_t)n * 32 + 255) / 256, 256, 0, stream>>>(logits, Xu, n);
  k_fill<<<(E + 255) / 256, 256, 0, stream>>>(ei, E, row_start, cursor, dinv, deg_i, ec);
  k_agg<<<(n + 3) / 4, 256, 0, stream>>>(Xu, Ztu, row_start, ec, deg_i, Emb1, Emb2, dinv, n);
  int waves = (n + 63) / 64;
  k_final<<<waves, 64, 0, stream>>>(Ztu, logits, CFG, deg_i, W0, b0, W1, b1, W2, b2,
                                    Embg, wg, (float*)d_out, n);
}

// Round 13
// 572.649 us; speedup vs baseline: 1.1067x; 1.1067x over previous
//
#include <hip/hip_runtime.h>
#include <hip/hip_bf16.h>
#include <math.h>

// GETS calibrator: MoE-GCN. N nodes, E edges, C=64, F=512, FH=32, DH=16.
// R13: k_final split 4-way by output columns (block = node-group x col-group,
//      comb[16]/wave) -- R12 showed the grid had only 1563 waves vs 1024 SIMDs
//      (1.5 waves/SIMD grid-cap), so s_load K$ fills could not be hidden.

#define XD 160   // aggregated feature dim (Zt layout)
#define CC 64    // classes
#define NREP 4   // counter replicas

typedef __attribute__((ext_vector_type(8))) short short8;
typedef __attribute__((ext_vector_type(4))) float f32x4;

static __device__ inline unsigned pk_bf16(float a, float b) {
  __hip_bfloat162 h;
  h.x = __float2bfloat16(a);
  h.y = __float2bfloat16(b);
  return *reinterpret_cast<unsigned*>(&h);
}
static __device__ inline unsigned short bf16u(float f) {
  __hip_bfloat16 h = __float2bfloat16(f);
  return *reinterpret_cast<unsigned short*>(&h);
}
static __device__ inline float bf_lo(unsigned u) {
  unsigned v = u << 16;
  return __builtin_bit_cast(float, v);
}
static __device__ inline float bf_hi(unsigned u) {
  unsigned v = u & 0xffff0000u;
  return __builtin_bit_cast(float, v);
}

// ---------------- degree counting: packed (outdeg<<16 | indeg), 4 replicas ----------------
__global__ void k_degrees(const int* __restrict__ ei, int E,
                          unsigned* __restrict__ cntP, int n) {
  int e = blockIdx.x * blockDim.x + threadIdx.x;
  if (e >= E) return;
  int s = ei[e], d = ei[E + e];
  unsigned r = threadIdx.x & (NREP - 1);
  atomicAdd(&cntP[r * (size_t)n + d], 1u);        // indeg
  atomicAdd(&cntP[r * (size_t)n + s], 0x10000u);  // outdeg
}

// ---------------- 2-level exclusive scan of indeg -> row_start ----------------
__global__ void k_scan1(const unsigned* __restrict__ cntP, int n, int* __restrict__ bsum) {
  __shared__ int red[1024];
  int tid = threadIdx.x;
  int i = blockIdx.x * 1024 + tid;
  int v = 0;
  if (i < n) {
    unsigned t = 0;
#pragma unroll
    for (int r = 0; r < NREP; ++r) t += cntP[r * (size_t)n + i];
    v = (int)(t & 0xFFFFu);
  }
  red[tid] = v;
  __syncthreads();
  for (int s = 512; s > 0; s >>= 1) {
    if (tid < s) red[tid] += red[tid + s];
    __syncthreads();
  }
  if (tid == 0) bsum[blockIdx.x] = red[0];
}

__global__ void k_scan2(int* __restrict__ bsum, int nb, int* __restrict__ row_start, int n) {
  if (threadIdx.x == 0 && blockIdx.x == 0) {
    int run = 0;
    for (int b = 0; b < nb; ++b) { int t = bsum[b]; bsum[b] = run; run += t; }
    row_start[n] = run;   // == E
  }
}

__global__ void k_scan3(const unsigned* __restrict__ cntP, int n, const int* __restrict__ bsum,
                        int* __restrict__ row_start, float* __restrict__ dinv,
                        int* __restrict__ deg_i) {
  __shared__ int sc[1024];
  int tid = threadIdx.x;
  int i = blockIdx.x * 1024 + tid;
  int indeg = 0, total = 0;
  if (i < n) {
    unsigned t = 0;
#pragma unroll
    for (int r = 0; r < NREP; ++r) t += cntP[r * (size_t)n + i];
    indeg = (int)(t & 0xFFFFu);
    total = indeg + (int)(t >> 16);
  }
  sc[tid] = indeg;
  __syncthreads();
  for (int ofs = 1; ofs < 1024; ofs <<= 1) {
    int t = (tid >= ofs) ? sc[tid - ofs] : 0;
    __syncthreads();
    sc[tid] += t;
    __syncthreads();
  }
  if (i < n) {
    int incl = sc[tid];
    row_start[i] = incl - indeg + bsum[blockIdx.x];
    dinv[i] = rsqrtf((float)indeg + 1.0f);   // GCN deg = indeg + 1 (self loop)
    deg_i[i] = total;                        // embedding degree = indeg + outdeg
  }
}

// ---------------- CSR fill: (src | deg<<20, coef) per edge ----------------
__global__ void k_fill(const int* __restrict__ ei, int E, const int* __restrict__ row_start,
                       int* __restrict__ cursor, const float* __restrict__ dinv,
                       const int* __restrict__ deg_i, int2* __restrict__ ec) {
  int e = blockIdx.x * blockDim.x + threadIdx.x;
  if (e >= E) return;
  int s = ei[e], d = ei[E + e];
  int pos = row_start[d] + atomicAdd(&cursor[d], 1);
  int dg = deg_i[s]; if (dg > 127) dg = 127;
  int2 v;
  v.x = s | (dg << 20);
  v.y = __float_as_int(dinv[s] * dinv[d]);
  ec[pos] = v;
}

// ---------------- Wv = Wfg(512x32) @ wg[64:96] (3 cols), fp32 ----------------
__global__ void k_wv(const float* __restrict__ Wfg, const float* __restrict__ bfg,
                     const float* __restrict__ wg, float* __restrict__ Wv4) {
  int k = blockIdx.x * blockDim.x + threadIdx.x;
  if (k >= 512) return;
  float a0 = 0.f, a1 = 0.f, a2 = 0.f;
  for (int j = 0; j < 32; ++j) {
    float w = Wfg[k * 32 + j];
    a0 += w * wg[(64 + j) * 3 + 0];
    a1 += w * wg[(64 + j) * 3 + 1];
    a2 += w * wg[(64 + j) * 3 + 2];
  }
  float4 v; v.x = a0; v.y = a1; v.z = a2; v.w = 0.f;
  *(float4*)&Wv4[k * 4] = v;
  if (k == 0) {
    float c0 = 0.f, c1 = 0.f, c2 = 0.f;
    for (int j = 0; j < 32; ++j) {
      float b = bfg[j];
      c0 += b * wg[(64 + j) * 3 + 0];
      c1 += b * wg[(64 + j) * 3 + 1];
      c2 += b * wg[(64 + j) * 3 + 2];
    }
    float4 c; c.x = c0; c.y = c1; c.z = c2; c.w = 0.f;
    *(float4*)&Wv4[512 * 4] = c;
  }
}

// ---------------- k_projm: bf16 MFMA  feat(n,512) @ [Wf0|Wf2](512,64) + fp32 CFG -------
// Xu row 64 uints (256B): [logits pairs u0..31 | f0 u32..47 | f2 u48..63]
__global__ __launch_bounds__(256) void k_projm(
    const float* __restrict__ feat,
    const float* __restrict__ Wf0, const float* __restrict__ bf0,
    const float* __restrict__ Wf2, const float* __restrict__ bf2,
    const float* __restrict__ Wv4,
    unsigned* __restrict__ Xu, float* __restrict__ CFG, int n) {
  __shared__ unsigned short Al[2][64][40];    // [buf][node][k 0..31 bf16], 80B row (16B pad)
  __shared__ unsigned short Bs[2][4][64][8];  // [buf][ntile][lane][j] frag-ordered

  int t = threadIdx.x;
  int l = t & 63;
  int w = t >> 6;
  int blk = blockIdx.x;

  int node_s = t >> 2;            // 0..63
  int kq = t & 3;                 // k-quarter within the 32-wide K-step
  int gn_s = blk * 64 + node_s;
  int gn_c = gn_s < n ? gn_s : n - 1;
  const float* frow = feat + (size_t)gn_c * 512 + kq * 8;

  int bk = (l >> 4) * 8;                    // k_local base
  int bc = (w << 4) + (l & 15);             // col 0..63
  const float* wsrc = (bc < 32) ? (Wf0 + bc) : (Wf2 + (bc - 32));

  float cfg0 = 0.f, cfg1 = 0.f, cfg2 = 0.f;

  auto stage = [&](int ks, int buf) {
    float4 fa = *(const float4*)&frow[ks * 32];
    float4 fb = *(const float4*)&frow[ks * 32 + 4];
    float fv[8] = {fa.x, fa.y, fa.z, fa.w, fb.x, fb.y, fb.z, fb.w};
    const float* wv = Wv4 + (ks * 32 + kq * 8) * 4;
#pragma unroll
    for (int j = 0; j < 8; ++j) {
      float4 v = *(const float4*)&wv[j * 4];
      cfg0 += fv[j] * v.x;
      cfg1 += fv[j] * v.y;
      cfg2 += fv[j] * v.z;
    }
    unsigned short pa[8];
#pragma unroll
    for (int j = 0; j < 8; ++j) pa[j] = bf16u(fv[j]);
    *(uint4*)&Al[buf][node_s][kq * 8] = *(const uint4*)pa;
    unsigned short pb[8];
#pragma unroll
    for (int j = 0; j < 8; ++j)
      pb[j] = bf16u(wsrc[(size_t)(ks * 32 + bk + j) * 32]);
    *(uint4*)&Bs[buf][w][l][0] = *(const uint4*)pb;
  };

  f32x4 acc[4];
#pragma unroll
  for (int q = 0; q < 4; ++q) acc[q] = (f32x4){0.f, 0.f, 0.f, 0.f};

  stage(0, 0);
  int cur = 0;
  for (int ks = 0; ks < 16; ++ks) {
    __syncthreads();
    if (ks < 15) stage(ks + 1, cur ^ 1);
    short8 af = *(const short8*)&Al[cur][(w << 4) + (l & 15)][(l >> 4) * 8];
#pragma unroll
    for (int nt = 0; nt < 4; ++nt) {
      short8 bfv = *(const short8*)&Bs[cur][nt][l][0];
      acc[nt] = __builtin_amdgcn_mfma_f32_16x16x32_bf16(af, bfv, acc[nt], 0, 0, 0);
    }
    cur ^= 1;
  }

  cfg0 += __shfl_xor(cfg0, 1); cfg0 += __shfl_xor(cfg0, 2);
  cfg1 += __shfl_xor(cfg1, 1); cfg1 += __shfl_xor(cfg1, 2);
  cfg2 += __shfl_xor(cfg2, 1); cfg2 += __shfl_xor(cfg2, 2);
  if (kq == 0 && gn_s < n) {
    float4 cc = *(const float4*)&Wv4[512 * 4];
    CFG[gn_s] = cfg0 + cc.x;
    CFG[n + gn_s] = cfg1 + cc.y;
    CFG[2 * (size_t)n + gn_s] = cfg2 + cc.z;
  }

  // ---- store X (bf16): D[row=(l>>4)*4+r][col=nt*16+(l&15)]; feature = 64+col ----
  unsigned short* Xus = (unsigned short*)Xu;
#pragma unroll
  for (int nt = 0; nt < 4; ++nt) {
    int col = (nt << 4) + (l & 15);
    float bias = (col < 32) ? bf0[col] : bf2[col - 32];
    int fidx = 64 + col;   // f0 -> 64..95, f2 -> 96..127 (compact layout)
#pragma unroll
    for (int r = 0; r < 4; ++r) {
      int nd = blk * 64 + (w << 4) + ((l >> 4) << 2) + r;
      if (nd < n) Xus[(size_t)nd * 128 + fidx] = bf16u(acc[nt][r] + bias);
    }
  }
}

// ---------------- build X (bf16): logits pairs ----------------
__global__ void k_buildx(const float* __restrict__ logits,
                         unsigned* __restrict__ Xu, int n) {
  int gid = blockIdx.x * blockDim.x + threadIdx.x;
  if (gid >= n * 32) return;
  int node = gid >> 5, p = gid & 31;
  const float* lgr = logits + (size_t)node * 64;
  float2 lg = *(const float2*)&lgr[2 * p];
  Xu[(size_t)node * 64 + p] = pk_bf16(lg.x, lg.y);
}

// ---------------- aggregation: Zt(bf16) = A_hat @ [Xu(256B rows) | Emb(packed deg)] ------
__global__ __launch_bounds__(256) void k_agg(
    const unsigned* __restrict__ Xu, unsigned* __restrict__ Ztu,
    const int* __restrict__ row_start, const int2* __restrict__ ec,
    const int* __restrict__ deg_i,
    const float* __restrict__ Emb1, const float* __restrict__ Emb2,
    const float* __restrict__ dinv, int n) {
  int w = threadIdx.x >> 6, l = threadIdx.x & 63;
  int node = blockIdx.x * 4 + w;
  if (node >= n) return;
  int beg = row_start[node], end = row_start[node + 1];

  const float* etab = (l < 8) ? (Emb1 + 2 * l) : (Emb2 + 2 * (l - 8));

  float ax = 0.f, ay = 0.f, bx = 0.f, by = 0.f;
  int i = beg;
  for (; i + 2 <= end; i += 2) {
    int2 e0 = ec[i];
    int2 e1 = ec[i + 1];
    int s0 = e0.x & 0xFFFFF;
    int s1 = e1.x & 0xFFFFF;
    float c0 = __int_as_float(e0.y);
    float c1 = __int_as_float(e1.y);
    unsigned u0 = Xu[(size_t)s0 * 64 + l];
    unsigned u1 = Xu[(size_t)s1 * 64 + l];
    ax += c0 * bf_lo(u0); ay += c0 * bf_hi(u0);
    ax += c1 * bf_lo(u1); ay += c1 * bf_hi(u1);
    if (l < 16) {
      float2 ev0 = *(const float2*)&etab[(e0.x >> 20) * 16];
      float2 ev1 = *(const float2*)&etab[(e1.x >> 20) * 16];
      bx += c0 * ev0.x; by += c0 * ev0.y;
      bx += c1 * ev1.x; by += c1 * ev1.y;
    }
  }
  if (i < end) {
    int2 e0 = ec[i];
    int s0 = e0.x & 0xFFFFF;
    float c0 = __int_as_float(e0.y);
    unsigned u0 = Xu[(size_t)s0 * 64 + l];
    ax += c0 * bf_lo(u0); ay += c0 * bf_hi(u0);
    if (l < 16) {
      float2 ev0 = *(const float2*)&etab[(e0.x >> 20) * 16];
      bx += c0 * ev0.x; by += c0 * ev0.y;
    }
  }
  // self loop
  float di = dinv[node];
  float c2 = di * di;
  {
    unsigned u = Xu[(size_t)node * 64 + l];
    ax += c2 * bf_lo(u);
    ay += c2 * bf_hi(u);
    if (l < 16) {
      int dg = deg_i[node]; if (dg > 127) dg = 127;
      float2 ev = *(const float2*)&etab[dg * 16];
      bx += c2 * ev.x;
      by += c2 * ev.y;
    }
  }
  // main store: new feature nf=2l -> old feature (nf<96 ? nf : nf+16)
  {
    int nf = 2 * l;
    int of = nf + (nf >= 96 ? 16 : 0);
    Ztu[2 * ((size_t)(of >> 2) * n + node) + ((of >> 1) & 1)] = pk_bf16(ax, ay);
  }
  if (l < 16) {
    int p = l & 7;
    int of = (l < 8) ? (96 + 2 * p) : (144 + 2 * p);
    Ztu[2 * ((size_t)(of >> 2) * n + node) + (p & 1)] = pk_bf16(bx, by);
  }
}

// ---------------- final: 4-way column split, 1 wave/block, comb[16] ----------------
// block b: node group b>>2 (64 nodes, lane=node), column group b&3 (16 cols).
__global__ __launch_bounds__(64) void k_final(
    const unsigned* __restrict__ Ztu, const float* __restrict__ logits,
    const float* __restrict__ CFG, const int* __restrict__ deg_i,
    const float* __restrict__ W0, const float* __restrict__ b0,
    const float* __restrict__ W1, const float* __restrict__ b1,
    const float* __restrict__ W2, const float* __restrict__ b2,
    const float* __restrict__ Embg, const float* __restrict__ wg,
    float* __restrict__ out, int n) {
  int l = threadIdx.x;
  int g = blockIdx.x >> 2;
  int cb = (blockIdx.x & 3) * 16;      // column base
  int node = g * 64 + l;
  int nc = node < n ? node : n - 1;

  // ---- gating (fp32, full; identical in all 4 col-groups) ----
  float c0 = 0.f, c1 = 0.f, c2 = 0.f;
  const float* lgr = logits + (size_t)nc * 64;
#pragma unroll
  for (int q = 0; q < 16; ++q) {
    float4 v = *(const float4*)&lgr[q * 4];
    const float* p = (const float*)&v;
#pragma unroll
    for (int j = 0; j < 4; ++j) {
      int k = q * 4 + j;
      c0 += p[j] * wg[k * 3 + 0];
      c1 += p[j] * wg[k * 3 + 1];
      c2 += p[j] * wg[k * 3 + 2];
    }
  }
  {
    int dg = deg_i[nc]; if (dg > 127) dg = 127;
    const float* egr = Embg + dg * 16;
#pragma unroll
    for (int q = 0; q < 4; ++q) {
      float4 v = *(const float4*)&egr[q * 4];
      const float* p = (const float*)&v;
#pragma unroll
      for (int j = 0; j < 4; ++j) {
        int k = 96 + q * 4 + j;
        c0 += p[j] * wg[k * 3 + 0];
        c1 += p[j] * wg[k * 3 + 1];
        c2 += p[j] * wg[k * 3 + 2];
      }
    }
  }
  c0 += CFG[nc];
  c1 += CFG[n + nc];
  c2 += CFG[2 * (size_t)n + nc];

  int i0 = 0; float t0 = c0;
  if (c1 > t0) { t0 = c1; i0 = 1; }
  if (c2 > t0) { t0 = c2; i0 = 2; }
  float t1 = -3.4e38f; int i1 = 0;
  if (i0 != 0) { t1 = c0; i1 = 0; }
  if (i0 != 1 && c1 > t1) { t1 = c1; i1 = 1; }
  if (i0 != 2 && c2 > t1) { t1 = c2; i1 = 2; }
  float e1v = expf(t1 - t0);
  float gsum = 1.0f + e1v;
  float gA = 1.0f / gsum, gB = e1v / gsum;
  float g0 = (i0 == 0) ? gA : (i1 == 0) ? gB : 0.f;
  float g1 = (i0 == 1) ? gA : (i1 == 1) ? gB : 0.f;
  float g2 = (i0 == 2) ? gA : (i1 == 2) ? gB : 0.f;

  float comb[16];
#pragma unroll
  for (int c = 0; c < 16; ++c) comb[c] = 0.f;

#define CHUNK(CIDX, GE, WPTR, KROW)                                        \
  {                                                                        \
    uint2 zu = *(const uint2*)&Ztu[2 * ((size_t)(CIDX) * n + nc)];         \
    float zs[4] = {(GE) * bf_lo(zu.x), (GE) * bf_hi(zu.x),                 \
                   (GE) * bf_lo(zu.y), (GE) * bf_hi(zu.y)};                \
    const float* wr = (WPTR) + (KROW) * 64 + cb;                           \
    _Pragma("unroll") for (int kk = 0; kk < 4; ++kk) {                     \
      float zz = zs[kk];                                                   \
      const float* wrow = wr + kk * 64;                                    \
      _Pragma("unroll") for (int c = 0; c < 16; ++c)                       \
        comb[c] += zz * wrow[c];                                           \
    }                                                                      \
  }

  for (int t = 0; t < 24; ++t) CHUNK(t, g0, W0, 4 * t);
  for (int t = 0; t < 16; ++t) CHUNK(t, g1, W1, 4 * t);
  for (int t = 0; t < 4; ++t)  CHUNK(24 + t, g1, W1, 64 + 4 * t);
  for (int t = 0; t < 12; ++t) CHUNK(28 + t, g2, W2, 4 * t);
#undef CHUNK

#pragma unroll
  for (int c = 0; c < 16; ++c)
    comb[c] += g0 * b0[cb + c] + g1 * b1[cb + c] + g2 * b2[cb + c];

  if (node < n) {
    float* outr = out + (size_t)node * 64 + cb;
#pragma unroll
    for (int q = 0; q < 4; ++q) {
      float4 lg4 = *(const float4*)&lgr[cb + q * 4];
      const float* pl = (const float*)&lg4;
      float4 o;
      float* po = (float*)&o;
#pragma unroll
      for (int j = 0; j < 4; ++j) {
        float v = comb[q * 4 + j];
        float sp = fmaxf(v, 0.f) + log1pf(expf(-fabsf(v)));
        po[j] = pl[j] * sp;
      }
      *(float4*)&outr[q * 4] = o;
    }
  }
}

extern "C" void kernel_launch(void* const* d_in, const int* in_sizes, int n_in,
                              void* d_out, int out_size, void* d_ws, size_t ws_size,
                              hipStream_t stream) {
  const float* logits = (const float*)d_in[0];
  const float* feat   = (const float*)d_in[1];
  const int*   ei     = (const int*)d_in[2];
  const float* Wf0 = (const float*)d_in[3];
  const float* bf0 = (const float*)d_in[4];
  const float* W0  = (const float*)d_in[5];
  const float* b0  = (const float*)d_in[6];
  const float* Emb1= (const float*)d_in[7];
  const float* W1  = (const float*)d_in[8];
  const float* b1  = (const float*)d_in[9];
  const float* Wf2 = (const float*)d_in[10];
  const float* bf2 = (const float*)d_in[11];
  const float* Emb2= (const float*)d_in[12];
  const float* W2  = (const float*)d_in[13];
  const float* b2  = (const float*)d_in[14];
  const float* Wfg = (const float*)d_in[15];
  const float* bfg = (const float*)d_in[16];
  const float* Embg= (const float*)d_in[17];
  const float* wg  = (const float*)d_in[18];

  int n = in_sizes[0] / 64;
  int E = in_sizes[2] / 2;

  char* base = (char*)d_ws;
  size_t off = 0;
  auto alloc = [&](size_t bytes) -> void* {
    void* p = base + off;
    off += bytes;
    off = (off + 255) & ~(size_t)255;
    return p;
  };
  unsigned* cntP   = (unsigned*)alloc((size_t)NREP * n * 4);
  int*   cursor    = (int*)alloc((size_t)n * 4);
  size_t zero_bytes = off;                 // cntP + cursor
  int*   deg_i     = (int*)alloc((size_t)n * 4);
  int*   row_start = (int*)alloc(((size_t)n + 1) * 4);
  int*   bsum      = (int*)alloc(1024 * 4);
  float* dinv      = (float*)alloc((size_t)n * 4);
  int2*  ec        = (int2*)alloc((size_t)E * 8);
  float* CFG       = (float*)alloc((size_t)n * 3 * 4);
  float* Wv4       = (float*)alloc((size_t)513 * 4 * 4);
  unsigned* Xu     = (unsigned*)alloc((size_t)n * 64 * 4);   // bf16 X: 128 feat x 2B
  unsigned* Ztu    = (unsigned*)alloc((size_t)n * 80 * 4);   // bf16 Zt (160 feat)
  (void)ws_size;

  hipMemsetAsync(base, 0, zero_bytes, stream);

  int nb_scan = (n + 1023) / 1024;
  k_degrees<<<(E + 255) / 256, 256, 0, stream>>>(ei, E, cntP, n);
  k_scan1<<<nb_scan, 1024, 0, stream>>>(cntP, n, bsum);
  k_scan2<<<1, 64, 0, stream>>>(bsum, nb_scan, row_start, n);
  k_scan3<<<nb_scan, 1024, 0, stream>>>(cntP, n, bsum, row_start, dinv, deg_i);
  k_wv<<<2, 256, 0, stream>>>(Wfg, bfg, wg, Wv4);
  k_projm<<<(n + 63) / 64, 256, 0, stream>>>(feat, Wf0, bf0, Wf2, bf2, Wv4, Xu, CFG, n);
  k_buildx<<<((size_t)n * 32 + 255) / 256, 256, 0, stream>>>(logits, Xu, n);
  k_fill<<<(E + 255) / 256, 256, 0, stream>>>(ei, E, row_start, cursor, dinv, deg_i, ec);
  k_agg<<<(n + 3) / 4, 256, 0, stream>>>(Xu, Ztu, row_start, ec, deg_i, Emb1, Emb2, dinv, n);
  int waves = (n + 63) / 64;
  k_final<<<waves * 4, 64, 0, stream>>>(Ztu, logits, CFG, deg_i, W0, b0, W1, b1, W2, b2,
                                        Embg, wg, (float*)d_out, n);
}

// Round 14
// 555.510 us; speedup vs baseline: 1.1408x; 1.0309x over previous
//
#include <hip/hip_runtime.h>
#include <hip/hip_bf16.h>
#include <math.h>

// GETS calibrator: MoE-GCN. N nodes, E edges, C=64, F=512, FH=32, DH=16.
// R14: k_agg edge loop unrolled x4 (2x MLP -- R13 showed 37% VALU, 25% of BW:
//      latency/MLP-bound with only 2 gathers in flight). k_degrees NREP 4->8.

#define XD 160   // aggregated feature dim (Zt layout)
#define CC 64    // classes
#define NREP 8   // counter replicas

typedef __attribute__((ext_vector_type(8))) short short8;
typedef __attribute__((ext_vector_type(4))) float f32x4;

static __device__ inline unsigned pk_bf16(float a, float b) {
  __hip_bfloat162 h;
  h.x = __float2bfloat16(a);
  h.y = __float2bfloat16(b);
  return *reinterpret_cast<unsigned*>(&h);
}
static __device__ inline unsigned short bf16u(float f) {
  __hip_bfloat16 h = __float2bfloat16(f);
  return *reinterpret_cast<unsigned short*>(&h);
}
static __device__ inline float bf_lo(unsigned u) {
  unsigned v = u << 16;
  return __builtin_bit_cast(float, v);
}
static __device__ inline float bf_hi(unsigned u) {
  unsigned v = u & 0xffff0000u;
  return __builtin_bit_cast(float, v);
}

// ---------------- degree counting: packed (outdeg<<16 | indeg), 8 replicas ----------------
__global__ void k_degrees(const int* __restrict__ ei, int E,
                          unsigned* __restrict__ cntP, int n) {
  int e = blockIdx.x * blockDim.x + threadIdx.x;
  if (e >= E) return;
  int s = ei[e], d = ei[E + e];
  unsigned r = threadIdx.x & (NREP - 1);
  atomicAdd(&cntP[r * (size_t)n + d], 1u);        // indeg
  atomicAdd(&cntP[r * (size_t)n + s], 0x10000u);  // outdeg
}

// ---------------- 2-level exclusive scan of indeg -> row_start ----------------
__global__ void k_scan1(const unsigned* __restrict__ cntP, int n, int* __restrict__ bsum) {
  __shared__ int red[1024];
  int tid = threadIdx.x;
  int i = blockIdx.x * 1024 + tid;
  int v = 0;
  if (i < n) {
    unsigned t = 0;
#pragma unroll
    for (int r = 0; r < NREP; ++r) t += cntP[r * (size_t)n + i];
    v = (int)(t & 0xFFFFu);
  }
  red[tid] = v;
  __syncthreads();
  for (int s = 512; s > 0; s >>= 1) {
    if (tid < s) red[tid] += red[tid + s];
    __syncthreads();
  }
  if (tid == 0) bsum[blockIdx.x] = red[0];
}

__global__ void k_scan2(int* __restrict__ bsum, int nb, int* __restrict__ row_start, int n) {
  if (threadIdx.x == 0 && blockIdx.x == 0) {
    int run = 0;
    for (int b = 0; b < nb; ++b) { int t = bsum[b]; bsum[b] = run; run += t; }
    row_start[n] = run;   // == E
  }
}

__global__ void k_scan3(const unsigned* __restrict__ cntP, int n, const int* __restrict__ bsum,
                        int* __restrict__ row_start, float* __restrict__ dinv,
                        int* __restrict__ deg_i) {
  __shared__ int sc[1024];
  int tid = threadIdx.x;
  int i = blockIdx.x * 1024 + tid;
  int indeg = 0, total = 0;
  if (i < n) {
    unsigned t = 0;
#pragma unroll
    for (int r = 0; r < NREP; ++r) t += cntP[r * (size_t)n + i];
    indeg = (int)(t & 0xFFFFu);
    total = indeg + (int)(t >> 16);
  }
  sc[tid] = indeg;
  __syncthreads();
  for (int ofs = 1; ofs < 1024; ofs <<= 1) {
    int t = (tid >= ofs) ? sc[tid - ofs] : 0;
    __syncthreads();
    sc[tid] += t;
    __syncthreads();
  }
  if (i < n) {
    int incl = sc[tid];
    row_start[i] = incl - indeg + bsum[blockIdx.x];
    dinv[i] = rsqrtf((float)indeg + 1.0f);   // GCN deg = indeg + 1 (self loop)
    deg_i[i] = total;                        // embedding degree = indeg + outdeg
  }
}

// ---------------- CSR fill: (src | deg<<20, coef) per edge ----------------
__global__ void k_fill(const int* __restrict__ ei, int E, const int* __restrict__ row_start,
                       int* __restrict__ cursor, const float* __restrict__ dinv,
                       const int* __restrict__ deg_i, int2* __restrict__ ec) {
  int e = blockIdx.x * blockDim.x + threadIdx.x;
  if (e >= E) return;
  int s = ei[e], d = ei[E + e];
  int pos = row_start[d] + atomicAdd(&cursor[d], 1);
  int dg = deg_i[s]; if (dg > 127) dg = 127;
  int2 v;
  v.x = s | (dg << 20);
  v.y = __float_as_int(dinv[s] * dinv[d]);
  ec[pos] = v;
}

// ---------------- Wv = Wfg(512x32) @ wg[64:96] (3 cols), fp32 ----------------
__global__ void k_wv(const float* __restrict__ Wfg, const float* __restrict__ bfg,
                     const float* __restrict__ wg, float* __restrict__ Wv4) {
  int k = blockIdx.x * blockDim.x + threadIdx.x;
  if (k >= 512) return;
  float a0 = 0.f, a1 = 0.f, a2 = 0.f;
  for (int j = 0; j < 32; ++j) {
    float w = Wfg[k * 32 + j];
    a0 += w * wg[(64 + j) * 3 + 0];
    a1 += w * wg[(64 + j) * 3 + 1];
    a2 += w * wg[(64 + j) * 3 + 2];
  }
  float4 v; v.x = a0; v.y = a1; v.z = a2; v.w = 0.f;
  *(float4*)&Wv4[k * 4] = v;
  if (k == 0) {
    float c0 = 0.f, c1 = 0.f, c2 = 0.f;
    for (int j = 0; j < 32; ++j) {
      float b = bfg[j];
      c0 += b * wg[(64 + j) * 3 + 0];
      c1 += b * wg[(64 + j) * 3 + 1];
      c2 += b * wg[(64 + j) * 3 + 2];
    }
    float4 c; c.x = c0; c.y = c1; c.z = c2; c.w = 0.f;
    *(float4*)&Wv4[512 * 4] = c;
  }
}

// ---------------- k_projm: bf16 MFMA  feat(n,512) @ [Wf0|Wf2](512,64) + fp32 CFG -------
// Xu row 64 uints (256B): [logits pairs u0..31 | f0 u32..47 | f2 u48..63]
__global__ __launch_bounds__(256) void k_projm(
    const float* __restrict__ feat,
    const float* __restrict__ Wf0, const float* __restrict__ bf0,
    const float* __restrict__ Wf2, const float* __restrict__ bf2,
    const float* __restrict__ Wv4,
    unsigned* __restrict__ Xu, float* __restrict__ CFG, int n) {
  __shared__ unsigned short Al[2][64][40];    // [buf][node][k 0..31 bf16], 80B row (16B pad)
  __shared__ unsigned short Bs[2][4][64][8];  // [buf][ntile][lane][j] frag-ordered

  int t = threadIdx.x;
  int l = t & 63;
  int w = t >> 6;
  int blk = blockIdx.x;

  int node_s = t >> 2;            // 0..63
  int kq = t & 3;                 // k-quarter within the 32-wide K-step
  int gn_s = blk * 64 + node_s;
  int gn_c = gn_s < n ? gn_s : n - 1;
  const float* frow = feat + (size_t)gn_c * 512 + kq * 8;

  int bk = (l >> 4) * 8;                    // k_local base
  int bc = (w << 4) + (l & 15);             // col 0..63
  const float* wsrc = (bc < 32) ? (Wf0 + bc) : (Wf2 + (bc - 32));

  float cfg0 = 0.f, cfg1 = 0.f, cfg2 = 0.f;

  auto stage = [&](int ks, int buf) {
    float4 fa = *(const float4*)&frow[ks * 32];
    float4 fb = *(const float4*)&frow[ks * 32 + 4];
    float fv[8] = {fa.x, fa.y, fa.z, fa.w, fb.x, fb.y, fb.z, fb.w};
    const float* wv = Wv4 + (ks * 32 + kq * 8) * 4;
#pragma unroll
    for (int j = 0; j < 8; ++j) {
      float4 v = *(const float4*)&wv[j * 4];
      cfg0 += fv[j] * v.x;
      cfg1 += fv[j] * v.y;
      cfg2 += fv[j] * v.z;
    }
    unsigned short pa[8];
#pragma unroll
    for (int j = 0; j < 8; ++j) pa[j] = bf16u(fv[j]);
    *(uint4*)&Al[buf][node_s][kq * 8] = *(const uint4*)pa;
    unsigned short pb[8];
#pragma unroll
    for (int j = 0; j < 8; ++j)
      pb[j] = bf16u(wsrc[(size_t)(ks * 32 + bk + j) * 32]);
    *(uint4*)&Bs[buf][w][l][0] = *(const uint4*)pb;
  };

  f32x4 acc[4];
#pragma unroll
  for (int q = 0; q < 4; ++q) acc[q] = (f32x4){0.f, 0.f, 0.f, 0.f};

  stage(0, 0);
  int cur = 0;
  for (int ks = 0; ks < 16; ++ks) {
    __syncthreads();
    if (ks < 15) stage(ks + 1, cur ^ 1);
    short8 af = *(const short8*)&Al[cur][(w << 4) + (l & 15)][(l >> 4) * 8];
#pragma unroll
    for (int nt = 0; nt < 4; ++nt) {
      short8 bfv = *(const short8*)&Bs[cur][nt][l][0];
      acc[nt] = __builtin_amdgcn_mfma_f32_16x16x32_bf16(af, bfv, acc[nt], 0, 0, 0);
    }
    cur ^= 1;
  }

  cfg0 += __shfl_xor(cfg0, 1); cfg0 += __shfl_xor(cfg0, 2);
  cfg1 += __shfl_xor(cfg1, 1); cfg1 += __shfl_xor(cfg1, 2);
  cfg2 += __shfl_xor(cfg2, 1); cfg2 += __shfl_xor(cfg2, 2);
  if (kq == 0 && gn_s < n) {
    float4 cc = *(const float4*)&Wv4[512 * 4];
    CFG[gn_s] = cfg0 + cc.x;
    CFG[n + gn_s] = cfg1 + cc.y;
    CFG[2 * (size_t)n + gn_s] = cfg2 + cc.z;
  }

  // ---- store X (bf16): D[row=(l>>4)*4+r][col=nt*16+(l&15)]; feature = 64+col ----
  unsigned short* Xus = (unsigned short*)Xu;
#pragma unroll
  for (int nt = 0; nt < 4; ++nt) {
    int col = (nt << 4) + (l & 15);
    float bias = (col < 32) ? bf0[col] : bf2[col - 32];
    int fidx = 64 + col;   // f0 -> 64..95, f2 -> 96..127 (compact layout)
#pragma unroll
    for (int r = 0; r < 4; ++r) {
      int nd = blk * 64 + (w << 4) + ((l >> 4) << 2) + r;
      if (nd < n) Xus[(size_t)nd * 128 + fidx] = bf16u(acc[nt][r] + bias);
    }
  }
}

// ---------------- build X (bf16): logits pairs ----------------
__global__ void k_buildx(const float* __restrict__ logits,
                         unsigned* __restrict__ Xu, int n) {
  int gid = blockIdx.x * blockDim.x + threadIdx.x;
  if (gid >= n * 32) return;
  int node = gid >> 5, p = gid & 31;
  const float* lgr = logits + (size_t)node * 64;
  float2 lg = *(const float2*)&lgr[2 * p];
  Xu[(size_t)node * 64 + p] = pk_bf16(lg.x, lg.y);
}

// ---------------- aggregation: Zt(bf16) = A_hat @ [Xu(256B rows) | Emb(packed deg)] ------
// Edge loop unrolled x4 for MLP: 4 independent 256B row-gathers in flight/wave.
__global__ __launch_bounds__(256) void k_agg(
    const unsigned* __restrict__ Xu, unsigned* __restrict__ Ztu,
    const int* __restrict__ row_start, const int2* __restrict__ ec,
    const int* __restrict__ deg_i,
    const float* __restrict__ Emb1, const float* __restrict__ Emb2,
    const float* __restrict__ dinv, int n) {
  int w = threadIdx.x >> 6, l = threadIdx.x & 63;
  int node = blockIdx.x * 4 + w;
  if (node >= n) return;
  int beg = row_start[node], end = row_start[node + 1];

  const float* etab = (l < 8) ? (Emb1 + 2 * l) : (Emb2 + 2 * (l - 8));

  float ax = 0.f, ay = 0.f, bx = 0.f, by = 0.f;
  int i = beg;
  for (; i + 4 <= end; i += 4) {
    int2 e0 = ec[i];
    int2 e1 = ec[i + 1];
    int2 e2 = ec[i + 2];
    int2 e3 = ec[i + 3];
    unsigned u0 = Xu[(size_t)(e0.x & 0xFFFFF) * 64 + l];
    unsigned u1 = Xu[(size_t)(e1.x & 0xFFFFF) * 64 + l];
    unsigned u2 = Xu[(size_t)(e2.x & 0xFFFFF) * 64 + l];
    unsigned u3 = Xu[(size_t)(e3.x & 0xFFFFF) * 64 + l];
    float c0 = __int_as_float(e0.y);
    float c1 = __int_as_float(e1.y);
    float c2 = __int_as_float(e2.y);
    float c3 = __int_as_float(e3.y);
    ax += c0 * bf_lo(u0); ay += c0 * bf_hi(u0);
    ax += c1 * bf_lo(u1); ay += c1 * bf_hi(u1);
    ax += c2 * bf_lo(u2); ay += c2 * bf_hi(u2);
    ax += c3 * bf_lo(u3); ay += c3 * bf_hi(u3);
    if (l < 16) {
      float2 ev0 = *(const float2*)&etab[(e0.x >> 20) * 16];
      float2 ev1 = *(const float2*)&etab[(e1.x >> 20) * 16];
      float2 ev2 = *(const float2*)&etab[(e2.x >> 20) * 16];
      float2 ev3 = *(const float2*)&etab[(e3.x >> 20) * 16];
      bx += c0 * ev0.x; by += c0 * ev0.y;
      bx += c1 * ev1.x; by += c1 * ev1.y;
      bx += c2 * ev2.x; by += c2 * ev2.y;
      bx += c3 * ev3.x; by += c3 * ev3.y;
    }
  }
  for (; i < end; ++i) {
    int2 e0 = ec[i];
    int s0 = e0.x & 0xFFFFF;
    float c0 = __int_as_float(e0.y);
    unsigned u0 = Xu[(size_t)s0 * 64 + l];
    ax += c0 * bf_lo(u0); ay += c0 * bf_hi(u0);
    if (l < 16) {
      float2 ev0 = *(const float2*)&etab[(e0.x >> 20) * 16];
      bx += c0 * ev0.x; by += c0 * ev0.y;
    }
  }
  // self loop
  float di = dinv[node];
  float c2s = di * di;
  {
    unsigned u = Xu[(size_t)node * 64 + l];
    ax += c2s * bf_lo(u);
    ay += c2s * bf_hi(u);
    if (l < 16) {
      int dg = deg_i[node]; if (dg > 127) dg = 127;
      float2 ev = *(const float2*)&etab[dg * 16];
      bx += c2s * ev.x;
      by += c2s * ev.y;
    }
  }
  // main store: new feature nf=2l -> old feature (nf<96 ? nf : nf+16)
  {
    int nf = 2 * l;
    int of = nf + (nf >= 96 ? 16 : 0);
    Ztu[2 * ((size_t)(of >> 2) * n + node) + ((of >> 1) & 1)] = pk_bf16(ax, ay);
  }
  if (l < 16) {
    int p = l & 7;
    int of = (l < 8) ? (96 + 2 * p) : (144 + 2 * p);
    Ztu[2 * ((size_t)(of >> 2) * n + node) + (p & 1)] = pk_bf16(bx, by);
  }
}

// ---------------- final: 4-way column split, 1 wave/block, comb[16] ----------------
__global__ __launch_bounds__(64) void k_final(
    const unsigned* __restrict__ Ztu, const float* __restrict__ logits,
    const float* __restrict__ CFG, const int* __restrict__ deg_i,
    const float* __restrict__ W0, const float* __restrict__ b0,
    const float* __restrict__ W1, const float* __restrict__ b1,
    const float* __restrict__ W2, const float* __restrict__ b2,
    const float* __restrict__ Embg, const float* __restrict__ wg,
    float* __restrict__ out, int n) {
  int l = threadIdx.x;
  int g = blockIdx.x >> 2;
  int cb = (blockIdx.x & 3) * 16;      // column base
  int node = g * 64 + l;
  int nc = node < n ? node : n - 1;

  // ---- gating (fp32, full; identical in all 4 col-groups) ----
  float c0 = 0.f, c1 = 0.f, c2 = 0.f;
  const float* lgr = logits + (size_t)nc * 64;
#pragma unroll
  for (int q = 0; q < 16; ++q) {
    float4 v = *(const float4*)&lgr[q * 4];
    const float* p = (const float*)&v;
#pragma unroll
    for (int j = 0; j < 4; ++j) {
      int k = q * 4 + j;
      c0 += p[j] * wg[k * 3 + 0];
      c1 += p[j] * wg[k * 3 + 1];
      c2 += p[j] * wg[k * 3 + 2];
    }
  }
  {
    int dg = deg_i[nc]; if (dg > 127) dg = 127;
    const float* egr = Embg + dg * 16;
#pragma unroll
    for (int q = 0; q < 4; ++q) {
      float4 v = *(const float4*)&egr[q * 4];
      const float* p = (const float*)&v;
#pragma unroll
      for (int j = 0; j < 4; ++j) {
        int k = 96 + q * 4 + j;
        c0 += p[j] * wg[k * 3 + 0];
        c1 += p[j] * wg[k * 3 + 1];
        c2 += p[j] * wg[k * 3 + 2];
      }
    }
  }
  c0 += CFG[nc];
  c1 += CFG[n + nc];
  c2 += CFG[2 * (size_t)n + nc];

  int i0 = 0; float t0 = c0;
  if (c1 > t0) { t0 = c1; i0 = 1; }
  if (c2 > t0) { t0 = c2; i0 = 2; }
  float t1 = -3.4e38f; int i1 = 0;
  if (i0 != 0) { t1 = c0; i1 = 0; }
  if (i0 != 1 && c1 > t1) { t1 = c1; i1 = 1; }
  if (i0 != 2 && c2 > t1) { t1 = c2; i1 = 2; }
  float e1v = expf(t1 - t0);
  float gsum = 1.0f + e1v;
  float gA = 1.0f / gsum, gB = e1v / gsum;
  float g0 = (i0 == 0) ? gA : (i1 == 0) ? gB : 0.f;
  float g1 = (i0 == 1) ? gA : (i1 == 1) ? gB : 0.f;
  float g2 = (i0 == 2) ? gA : (i1 == 2) ? gB : 0.f;

  float comb[16];
#pragma unroll
  for (int c = 0; c < 16; ++c) comb[c] = 0.f;

#define CHUNK(CIDX, GE, WPTR, KROW)                                        \
  {                                                                        \
    uint2 zu = *(const uint2*)&Ztu[2 * ((size_t)(CIDX) * n + nc)];         \
    float zs[4] = {(GE) * bf_lo(zu.x), (GE) * bf_hi(zu.x),                 \
                   (GE) * bf_lo(zu.y), (GE) * bf_hi(zu.y)};                \
    const float* wr = (WPTR) + (KROW) * 64 + cb;                           \
    _Pragma("unroll") for (int kk = 0; kk < 4; ++kk) {                     \
      float zz = zs[kk];                                                   \
      const float* wrow = wr + kk * 64;                                    \
      _Pragma("unroll") for (int c = 0; c < 16; ++c)                       \
        comb[c] += zz * wrow[c];                                           \
    }                                                                      \
  }

  for (int t = 0; t < 24; ++t) CHUNK(t, g0, W0, 4 * t);
  for (int t = 0; t < 16; ++t) CHUNK(t, g1, W1, 4 * t);
  for (int t = 0; t < 4; ++t)  CHUNK(24 + t, g1, W1, 64 + 4 * t);
  for (int t = 0; t < 12; ++t) CHUNK(28 + t, g2, W2, 4 * t);
#undef CHUNK

#pragma unroll
  for (int c = 0; c < 16; ++c)
    comb[c] += g0 * b0[cb + c] + g1 * b1[cb + c] + g2 * b2[cb + c];

  if (node < n) {
    float* outr = out + (size_t)node * 64 + cb;
#pragma unroll
    for (int q = 0; q < 4; ++q) {
      float4 lg4 = *(const float4*)&lgr[cb + q * 4];
      const float* pl = (const float*)&lg4;
      float4 o;
      float* po = (float*)&o;
#pragma unroll
      for (int j = 0; j < 4; ++j) {
        float v = comb[q * 4 + j];
        float sp = fmaxf(v, 0.f) + log1pf(expf(-fabsf(v)));
        po[j] = pl[j] * sp;
      }
      *(float4*)&outr[q * 4] = o;
    }
  }
}

extern "C" void kernel_launch(void* const* d_in, const int* in_sizes, int n_in,
                              void* d_out, int out_size, void* d_ws, size_t ws_size,
                              hipStream_t stream) {
  const float* logits = (const float*)d_in[0];
  const float* feat   = (const float*)d_in[1];
  const int*   ei     = (const int*)d_in[2];
  const float* Wf0 = (const float*)d_in[3];
  const float* bf0 = (const float*)d_in[4];
  const float* W0  = (const float*)d_in[5];
  const float* b0  = (const float*)d_in[6];
  const float* Emb1= (const float*)d_in[7];
  const float* W1  = (const float*)d_in[8];
  const float* b1  = (const float*)d_in[9];
  const float* Wf2 = (const float*)d_in[10];
  const float* bf2 = (const float*)d_in[11];
  const float* Emb2= (const float*)d_in[12];
  const float* W2  = (const float*)d_in[13];
  const float* b2  = (const float*)d_in[14];
  const float* Wfg = (const float*)d_in[15];
  const float* bfg = (const float*)d_in[16];
  const float* Embg= (const float*)d_in[17];
  const float* wg  = (const float*)d_in[18];

  int n = in_sizes[0] / 64;
  int E = in_sizes[2] / 2;

  char* base = (char*)d_ws;
  size_t off = 0;
  auto alloc = [&](size_t bytes) -> void* {
    void* p = base + off;
    off += bytes;
    off = (off + 255) & ~(size_t)255;
    return p;
  };
  unsigned* cntP   = (unsigned*)alloc((size_t)NREP * n * 4);
  int*   cursor    = (int*)alloc((size_t)n * 4);
  size_t zero_bytes = off;                 // cntP + cursor
  int*   deg_i     = (int*)alloc((size_t)n * 4);
  int*   row_start = (int*)alloc(((size_t)n + 1) * 4);
  int*   bsum      = (int*)alloc(1024 * 4);
  float* dinv      = (float*)alloc((size_t)n * 4);
  int2*  ec        = (int2*)alloc((size_t)E * 8);
  float* CFG       = (float*)alloc((size_t)n * 3 * 4);
  float* Wv4       = (float*)alloc((size_t)513 * 4 * 4);
  unsigned* Xu     = (unsigned*)alloc((size_t)n * 64 * 4);   // bf16 X: 128 feat x 2B
  unsigned* Ztu    = (unsigned*)alloc((size_t)n * 80 * 4);   // bf16 Zt (160 feat)
  (void)ws_size;

  hipMemsetAsync(base, 0, zero_bytes, stream);

  int nb_scan = (n + 1023) / 1024;
  k_degrees<<<(E + 255) / 256, 256, 0, stream>>>(ei, E, cntP, n);
  k_scan1<<<nb_scan, 1024, 0, stream>>>(cntP, n, bsum);
  k_scan2<<<1, 64, 0, stream>>>(bsum, nb_scan, row_start, n);
  k_scan3<<<nb_scan, 1024, 0, stream>>>(cntP, n, bsum, row_start, dinv, deg_i);
  k_wv<<<2, 256, 0, stream>>>(Wfg, bfg, wg, Wv4);
  k_projm<<<(n + 63) / 64, 256, 0, stream>>>(feat, Wf0, bf0, Wf2, bf2, Wv4, Xu, CFG, n);
  k_buildx<<<((size_t)n * 32 + 255) / 256, 256, 0, stream>>>(logits, Xu, n);
  k_fill<<<(E + 255) / 256, 256, 0, stream>>>(ei, E, row_start, cursor, dinv, deg_i, ec);
  k_agg<<<(n + 3) / 4, 256, 0, stream>>>(Xu, Ztu, row_start, ec, deg_i, Emb1, Emb2, dinv, n);
  int waves = (n + 63) / 64;
  k_final<<<waves * 4, 64, 0, stream>>>(Ztu, logits, CFG, deg_i, W0, b0, W1, b1, W2, b2,
                                        Embg, wg, (float*)d_out, n);
}

// Round 15
// 516.280 us; speedup vs baseline: 1.2275x; 1.0760x over previous
//
#include <hip/hip_runtime.h>
#include <hip/hip_bf16.h>
#include <math.h>

// GETS calibrator: MoE-GCN. N nodes, E edges, C=64, F=512, FH=32, DH=16.
// R15: k_projm rewritten barrier-free/LDS-free: 1 wave per 16 nodes, A-fragment
//      loaded per-lane direct from feat (same lane layout LDS provided), B from
//      a precomputed bf16 fragment-ordered Wb (k_wb, 64KB, L2-hot). R14 k_projm
//      was barrier-latency bound (VALU 9%, Mfma 2%: 700cyc load vs 150cyc MFMA
//      per barrier-locked K-step). CFG fp32 tree identical -> gating unchanged.

#define XD 160   // aggregated feature dim (Zt layout)
#define CC 64    // classes
#define NREP 8   // counter replicas

typedef __attribute__((ext_vector_type(8))) short short8;
typedef __attribute__((ext_vector_type(4))) float f32x4;

static __device__ inline unsigned pk_bf16(float a, float b) {
  __hip_bfloat162 h;
  h.x = __float2bfloat16(a);
  h.y = __float2bfloat16(b);
  return *reinterpret_cast<unsigned*>(&h);
}
static __device__ inline unsigned short bf16u(float f) {
  __hip_bfloat16 h = __float2bfloat16(f);
  return *reinterpret_cast<unsigned short*>(&h);
}
static __device__ inline float bf_lo(unsigned u) {
  unsigned v = u << 16;
  return __builtin_bit_cast(float, v);
}
static __device__ inline float bf_hi(unsigned u) {
  unsigned v = u & 0xffff0000u;
  return __builtin_bit_cast(float, v);
}

// ---------------- degree counting: packed (outdeg<<16 | indeg), 8 replicas ----------------
__global__ void k_degrees(const int* __restrict__ ei, int E,
                          unsigned* __restrict__ cntP, int n) {
  int e = blockIdx.x * blockDim.x + threadIdx.x;
  if (e >= E) return;
  int s = ei[e], d = ei[E + e];
  unsigned r = threadIdx.x & (NREP - 1);
  atomicAdd(&cntP[r * (size_t)n + d], 1u);        // indeg
  atomicAdd(&cntP[r * (size_t)n + s], 0x10000u);  // outdeg
}

// ---------------- 2-level exclusive scan of indeg -> row_start ----------------
__global__ void k_scan1(const unsigned* __restrict__ cntP, int n, int* __restrict__ bsum) {
  __shared__ int red[1024];
  int tid = threadIdx.x;
  int i = blockIdx.x * 1024 + tid;
  int v = 0;
  if (i < n) {
    unsigned t = 0;
#pragma unroll
    for (int r = 0; r < NREP; ++r) t += cntP[r * (size_t)n + i];
    v = (int)(t & 0xFFFFu);
  }
  red[tid] = v;
  __syncthreads();
  for (int s = 512; s > 0; s >>= 1) {
    if (tid < s) red[tid] += red[tid + s];
    __syncthreads();
  }
  if (tid == 0) bsum[blockIdx.x] = red[0];
}

__global__ void k_scan2(int* __restrict__ bsum, int nb, int* __restrict__ row_start, int n) {
  if (threadIdx.x == 0 && blockIdx.x == 0) {
    int run = 0;
    for (int b = 0; b < nb; ++b) { int t = bsum[b]; bsum[b] = run; run += t; }
    row_start[n] = run;   // == E
  }
}

__global__ void k_scan3(const unsigned* __restrict__ cntP, int n, const int* __restrict__ bsum,
                        int* __restrict__ row_start, float* __restrict__ dinv,
                        int* __restrict__ deg_i) {
  __shared__ int sc[1024];
  int tid = threadIdx.x;
  int i = blockIdx.x * 1024 + tid;
  int indeg = 0, total = 0;
  if (i < n) {
    unsigned t = 0;
#pragma unroll
    for (int r = 0; r < NREP; ++r) t += cntP[r * (size_t)n + i];
    indeg = (int)(t & 0xFFFFu);
    total = indeg + (int)(t >> 16);
  }
  sc[tid] = indeg;
  __syncthreads();
  for (int ofs = 1; ofs < 1024; ofs <<= 1) {
    int t = (tid >= ofs) ? sc[tid - ofs] : 0;
    __syncthreads();
    sc[tid] += t;
    __syncthreads();
  }
  if (i < n) {
    int incl = sc[tid];
    row_start[i] = incl - indeg + bsum[blockIdx.x];
    dinv[i] = rsqrtf((float)indeg + 1.0f);   // GCN deg = indeg + 1 (self loop)
    deg_i[i] = total;                        // embedding degree = indeg + outdeg
  }
}

// ---------------- CSR fill: (src | deg<<20, coef) per edge ----------------
__global__ void k_fill(const int* __restrict__ ei, int E, const int* __restrict__ row_start,
                       int* __restrict__ cursor, const float* __restrict__ dinv,
                       const int* __restrict__ deg_i, int2* __restrict__ ec) {
  int e = blockIdx.x * blockDim.x + threadIdx.x;
  if (e >= E) return;
  int s = ei[e], d = ei[E + e];
  int pos = row_start[d] + atomicAdd(&cursor[d], 1);
  int dg = deg_i[s]; if (dg > 127) dg = 127;
  int2 v;
  v.x = s | (dg << 20);
  v.y = __float_as_int(dinv[s] * dinv[d]);
  ec[pos] = v;
}

// ---------------- Wv = Wfg(512x32) @ wg[64:96] (3 cols), fp32 ----------------
__global__ void k_wv(const float* __restrict__ Wfg, const float* __restrict__ bfg,
                     const float* __restrict__ wg, float* __restrict__ Wv4) {
  int k = blockIdx.x * blockDim.x + threadIdx.x;
  if (k >= 512) return;
  float a0 = 0.f, a1 = 0.f, a2 = 0.f;
  for (int j = 0; j < 32; ++j) {
    float w = Wfg[k * 32 + j];
    a0 += w * wg[(64 + j) * 3 + 0];
    a1 += w * wg[(64 + j) * 3 + 1];
    a2 += w * wg[(64 + j) * 3 + 2];
  }
  float4 v; v.x = a0; v.y = a1; v.z = a2; v.w = 0.f;
  *(float4*)&Wv4[k * 4] = v;
  if (k == 0) {
    float c0 = 0.f, c1 = 0.f, c2 = 0.f;
    for (int j = 0; j < 32; ++j) {
      float b = bfg[j];
      c0 += b * wg[(64 + j) * 3 + 0];
      c1 += b * wg[(64 + j) * 3 + 1];
      c2 += b * wg[(64 + j) * 3 + 2];
    }
    float4 c; c.x = c0; c.y = c1; c.z = c2; c.w = 0.f;
    *(float4*)&Wv4[512 * 4] = c;
  }
}

// ---------------- k_wb: [Wf0|Wf2] -> bf16 fragment-ordered Wb ----------------
// Wb[((ks*4 + nt)*64 + l)*8 + j] = W[ks*32 + (l>>4)*8 + j][nt*16 + (l&15)]
__global__ void k_wb(const float* __restrict__ Wf0, const float* __restrict__ Wf2,
                     unsigned short* __restrict__ Wb) {
  int tid = blockIdx.x * blockDim.x + threadIdx.x;   // 4096 threads
  if (tid >= 16 * 4 * 64) return;
  int l = tid & 63;
  int nt = (tid >> 6) & 3;
  int ks = tid >> 8;
  int col = (nt << 4) + (l & 15);
  int rowb = ks * 32 + ((l >> 4) << 3);
  const float* wsrc = (col < 32) ? (Wf0 + col) : (Wf2 + (col - 32));
  unsigned short pb[8];
#pragma unroll
  for (int j = 0; j < 8; ++j)
    pb[j] = bf16u(wsrc[(size_t)(rowb + j) * 32]);
  *(uint4*)&Wb[(size_t)tid * 8] = *(const uint4*)pb;
}

// ---------------- k_projm: barrier-free bf16 MFMA + fused fp32 CFG ----------------
// 1 wave / block, 16 nodes / wave. A-frag per-lane direct from feat; B-frag from Wb.
// Xu row 64 uints (256B): [logits pairs u0..31 | f0 u32..47 | f2 u48..63]
__global__ __launch_bounds__(64) void k_projm(
    const float* __restrict__ feat,
    const unsigned short* __restrict__ Wb,
    const float* __restrict__ bf0, const float* __restrict__ bf2,
    const float* __restrict__ Wv4,
    unsigned* __restrict__ Xu, float* __restrict__ CFG, int n) {
  int l = threadIdx.x;
  int g = blockIdx.x;
  int node_in = g * 16 + (l & 15);
  int nc = node_in < n ? node_in : n - 1;
  const float* frow = feat + (size_t)nc * 512 + ((l >> 4) << 3);

  f32x4 acc[4];
#pragma unroll
  for (int q = 0; q < 4; ++q) acc[q] = (f32x4){0.f, 0.f, 0.f, 0.f};
  float cfg0 = 0.f, cfg1 = 0.f, cfg2 = 0.f;

  for (int ks = 0; ks < 16; ++ks) {
    float4 fa = *(const float4*)&frow[ks * 32];
    float4 fb = *(const float4*)&frow[ks * 32 + 4];
    float fv[8] = {fa.x, fa.y, fa.z, fa.w, fb.x, fb.y, fb.z, fb.w};
    // CFG partial (exact fp32, same per-quarter tree as before)
    const float* wv = Wv4 + (ks * 32 + ((l >> 4) << 3)) * 4;
#pragma unroll
    for (int j = 0; j < 8; ++j) {
      float4 v = *(const float4*)&wv[j * 4];
      cfg0 += fv[j] * v.x;
      cfg1 += fv[j] * v.y;
      cfg2 += fv[j] * v.z;
    }
    unsigned short pa[8];
#pragma unroll
    for (int j = 0; j < 8; ++j) pa[j] = bf16u(fv[j]);
    short8 af = *(const short8*)pa;
#pragma unroll
    for (int nt = 0; nt < 4; ++nt) {
      short8 bfv = *(const short8*)&Wb[(size_t)((ks * 4 + nt) * 64 + l) * 8];
      acc[nt] = __builtin_amdgcn_mfma_f32_16x16x32_bf16(af, bfv, acc[nt], 0, 0, 0);
    }
  }

  // CFG reduce over the 4 k-quarters (lanes l, l+16, l+32, l+48)
  cfg0 += __shfl_xor(cfg0, 16); cfg0 += __shfl_xor(cfg0, 32);
  cfg1 += __shfl_xor(cfg1, 16); cfg1 += __shfl_xor(cfg1, 32);
  cfg2 += __shfl_xor(cfg2, 16); cfg2 += __shfl_xor(cfg2, 32);
  if (l < 16 && node_in < n) {
    float4 cc = *(const float4*)&Wv4[512 * 4];
    CFG[node_in] = cfg0 + cc.x;
    CFG[n + node_in] = cfg1 + cc.y;
    CFG[2 * (size_t)n + node_in] = cfg2 + cc.z;
  }

  // ---- store X (bf16): D[row=(l>>4)*4+r][col=nt*16+(l&15)]; feature = 64+col ----
  unsigned short* Xus = (unsigned short*)Xu;
#pragma unroll
  for (int nt = 0; nt < 4; ++nt) {
    int col = (nt << 4) + (l & 15);
    float bias = (col < 32) ? bf0[col] : bf2[col - 32];
    int fidx = 64 + col;
#pragma unroll
    for (int r = 0; r < 4; ++r) {
      int nd = g * 16 + ((l >> 4) << 2) + r;
      if (nd < n) Xus[(size_t)nd * 128 + fidx] = bf16u(acc[nt][r] + bias);
    }
  }
}

// ---------------- build X (bf16): logits pairs ----------------
__global__ void k_buildx(const float* __restrict__ logits,
                         unsigned* __restrict__ Xu, int n) {
  int gid = blockIdx.x * blockDim.x + threadIdx.x;
  if (gid >= n * 32) return;
  int node = gid >> 5, p = gid & 31;
  const float* lgr = logits + (size_t)node * 64;
  float2 lg = *(const float2*)&lgr[2 * p];
  Xu[(size_t)node * 64 + p] = pk_bf16(lg.x, lg.y);
}

// ---------------- aggregation: Zt(bf16) = A_hat @ [Xu(256B rows) | Emb(packed deg)] ------
__global__ __launch_bounds__(256) void k_agg(
    const unsigned* __restrict__ Xu, unsigned* __restrict__ Ztu,
    const int* __restrict__ row_start, const int2* __restrict__ ec,
    const int* __restrict__ deg_i,
    const float* __restrict__ Emb1, const float* __restrict__ Emb2,
    const float* __restrict__ dinv, int n) {
  int w = threadIdx.x >> 6, l = threadIdx.x & 63;
  int node = blockIdx.x * 4 + w;
  if (node >= n) return;
  int beg = row_start[node], end = row_start[node + 1];

  const float* etab = (l < 8) ? (Emb1 + 2 * l) : (Emb2 + 2 * (l - 8));

  float ax = 0.f, ay = 0.f, bx = 0.f, by = 0.f;
  int i = beg;
  for (; i + 4 <= end; i += 4) {
    int2 e0 = ec[i];
    int2 e1 = ec[i + 1];
    int2 e2 = ec[i + 2];
    int2 e3 = ec[i + 3];
    unsigned u0 = Xu[(size_t)(e0.x & 0xFFFFF) * 64 + l];
    unsigned u1 = Xu[(size_t)(e1.x & 0xFFFFF) * 64 + l];
    unsigned u2 = Xu[(size_t)(e2.x & 0xFFFFF) * 64 + l];
    unsigned u3 = Xu[(size_t)(e3.x & 0xFFFFF) * 64 + l];
    float c0 = __int_as_float(e0.y);
    float c1 = __int_as_float(e1.y);
    float c2 = __int_as_float(e2.y);
    float c3 = __int_as_float(e3.y);
    ax += c0 * bf_lo(u0); ay += c0 * bf_hi(u0);
    ax += c1 * bf_lo(u1); ay += c1 * bf_hi(u1);
    ax += c2 * bf_lo(u2); ay += c2 * bf_hi(u2);
    ax += c3 * bf_lo(u3); ay += c3 * bf_hi(u3);
    if (l < 16) {
      float2 ev0 = *(const float2*)&etab[(e0.x >> 20) * 16];
      float2 ev1 = *(const float2*)&etab[(e1.x >> 20) * 16];
      float2 ev2 = *(const float2*)&etab[(e2.x >> 20) * 16];
      float2 ev3 = *(const float2*)&etab[(e3.x >> 20) * 16];
      bx += c0 * ev0.x; by += c0 * ev0.y;
      bx += c1 * ev1.x; by += c1 * ev1.y;
      bx += c2 * ev2.x; by += c2 * ev2.y;
      bx += c3 * ev3.x; by += c3 * ev3.y;
    }
  }
  for (; i < end; ++i) {
    int2 e0 = ec[i];
    int s0 = e0.x & 0xFFFFF;
    float c0 = __int_as_float(e0.y);
    unsigned u0 = Xu[(size_t)s0 * 64 + l];
    ax += c0 * bf_lo(u0); ay += c0 * bf_hi(u0);
    if (l < 16) {
      float2 ev0 = *(const float2*)&etab[(e0.x >> 20) * 16];
      bx += c0 * ev0.x; by += c0 * ev0.y;
    }
  }
  // self loop
  float di = dinv[node];
  float c2s = di * di;
  {
    unsigned u = Xu[(size_t)node * 64 + l];
    ax += c2s * bf_lo(u);
    ay += c2s * bf_hi(u);
    if (l < 16) {
      int dg = deg_i[node]; if (dg > 127) dg = 127;
      float2 ev = *(const float2*)&etab[dg * 16];
      bx += c2s * ev.x;
      by += c2s * ev.y;
    }
  }
  // main store: new feature nf=2l -> old feature (nf<96 ? nf : nf+16)
  {
    int nf = 2 * l;
    int of = nf + (nf >= 96 ? 16 : 0);
    Ztu[2 * ((size_t)(of >> 2) * n + node) + ((of >> 1) & 1)] = pk_bf16(ax, ay);
  }
  if (l < 16) {
    int p = l & 7;
    int of = (l < 8) ? (96 + 2 * p) : (144 + 2 * p);
    Ztu[2 * ((size_t)(of >> 2) * n + node) + (p & 1)] = pk_bf16(bx, by);
  }
}

// ---------------- final: 4-way column split, 1 wave/block, comb[16] ----------------
__global__ __launch_bounds__(64) void k_final(
    const unsigned* __restrict__ Ztu, const float* __restrict__ logits,
    const float* __restrict__ CFG, const int* __restrict__ deg_i,
    const float* __restrict__ W0, const float* __restrict__ b0,
    const float* __restrict__ W1, const float* __restrict__ b1,
    const float* __restrict__ W2, const float* __restrict__ b2,
    const float* __restrict__ Embg, const float* __restrict__ wg,
    float* __restrict__ out, int n) {
  int l = threadIdx.x;
  int g = blockIdx.x >> 2;
  int cb = (blockIdx.x & 3) * 16;      // column base
  int node = g * 64 + l;
  int nc = node < n ? node : n - 1;

  // ---- gating (fp32, full; identical in all 4 col-groups) ----
  float c0 = 0.f, c1 = 0.f, c2 = 0.f;
  const float* lgr = logits + (size_t)nc * 64;
#pragma unroll
  for (int q = 0; q < 16; ++q) {
    float4 v = *(const float4*)&lgr[q * 4];
    const float* p = (const float*)&v;
#pragma unroll
    for (int j = 0; j < 4; ++j) {
      int k = q * 4 + j;
      c0 += p[j] * wg[k * 3 + 0];
      c1 += p[j] * wg[k * 3 + 1];
      c2 += p[j] * wg[k * 3 + 2];
    }
  }
  {
    int dg = deg_i[nc]; if (dg > 127) dg = 127;
    const float* egr = Embg + dg * 16;
#pragma unroll
    for (int q = 0; q < 4; ++q) {
      float4 v = *(const float4*)&egr[q * 4];
      const float* p = (const float*)&v;
#pragma unroll
      for (int j = 0; j < 4; ++j) {
        int k = 96 + q * 4 + j;
        c0 += p[j] * wg[k * 3 + 0];
        c1 += p[j] * wg[k * 3 + 1];
        c2 += p[j] * wg[k * 3 + 2];
      }
    }
  }
  c0 += CFG[nc];
  c1 += CFG[n + nc];
  c2 += CFG[2 * (size_t)n + nc];

  int i0 = 0; float t0 = c0;
  if (c1 > t0) { t0 = c1; i0 = 1; }
  if (c2 > t0) { t0 = c2; i0 = 2; }
  float t1 = -3.4e38f; int i1 = 0;
  if (i0 != 0) { t1 = c0; i1 = 0; }
  if (i0 != 1 && c1 > t1) { t1 = c1; i1 = 1; }
  if (i0 != 2 && c2 > t1) { t1 = c2; i1 = 2; }
  float e1v = expf(t1 - t0);
  float gsum = 1.0f + e1v;
  float gA = 1.0f / gsum, gB = e1v / gsum;
  float g0 = (i0 == 0) ? gA : (i1 == 0) ? gB : 0.f;
  float g1 = (i0 == 1) ? gA : (i1 == 1) ? gB : 0.f;
  float g2 = (i0 == 2) ? gA : (i1 == 2) ? gB : 0.f;

  float comb[16];
#pragma unroll
  for (int c = 0; c < 16; ++c) comb[c] = 0.f;

#define CHUNK(CIDX, GE, WPTR, KROW)                                        \
  {                                                                        \
    uint2 zu = *(const uint2*)&Ztu[2 * ((size_t)(CIDX) * n + nc)];         \
    float zs[4] = {(GE) * bf_lo(zu.x), (GE) * bf_hi(zu.x),                 \
                   (GE) * bf_lo(zu.y), (GE) * bf_hi(zu.y)};                \
    const float* wr = (WPTR) + (KROW) * 64 + cb;                           \
    _Pragma("unroll") for (int kk = 0; kk < 4; ++kk) {                     \
      float zz = zs[kk];                                                   \
      const float* wrow = wr + kk * 64;                                    \
      _Pragma("unroll") for (int c = 0; c < 16; ++c)                       \
        comb[c] += zz * wrow[c];                                           \
    }                                                                      \
  }

  for (int t = 0; t < 24; ++t) CHUNK(t, g0, W0, 4 * t);
  for (int t = 0; t < 16; ++t) CHUNK(t, g1, W1, 4 * t);
  for (int t = 0; t < 4; ++t)  CHUNK(24 + t, g1, W1, 64 + 4 * t);
  for (int t = 0; t < 12; ++t) CHUNK(28 + t, g2, W2, 4 * t);
#undef CHUNK

#pragma unroll
  for (int c = 0; c < 16; ++c)
    comb[c] += g0 * b0[cb + c] + g1 * b1[cb + c] + g2 * b2[cb + c];

  if (node < n) {
    float* outr = out + (size_t)node * 64 + cb;
#pragma unroll
    for (int q = 0; q < 4; ++q) {
      float4 lg4 = *(const float4*)&lgr[cb + q * 4];
      const float* pl = (const float*)&lg4;
      float4 o;
      float* po = (float*)&o;
#pragma unroll
      for (int j = 0; j < 4; ++j) {
        float v = comb[q * 4 + j];
        float sp = fmaxf(v, 0.f) + log1pf(expf(-fabsf(v)));
        po[j] = pl[j] * sp;
      }
      *(float4*)&outr[q * 4] = o;
    }
  }
}

extern "C" void kernel_launch(void* const* d_in, const int* in_sizes, int n_in,
                              void* d_out, int out_size, void* d_ws, size_t ws_size,
                              hipStream_t stream) {
  const float* logits = (const float*)d_in[0];
  const float* feat   = (const float*)d_in[1];
  const int*   ei     = (const int*)d_in[2];
  const float* Wf0 = (const float*)d_in[3];
  const float* bf0 = (const float*)d_in[4];
  const float* W0  = (const float*)d_in[5];
  const float* b0  = (const float*)d_in[6];
  const float* Emb1= (const float*)d_in[7];
  const float* W1  = (const float*)d_in[8];
  const float* b1  = (const float*)d_in[9];
  const float* Wf2 = (const float*)d_in[10];
  const float* bf2 = (const float*)d_in[11];
  const float* Emb2= (const float*)d_in[12];
  const float* W2  = (const float*)d_in[13];
  const float* b2  = (const float*)d_in[14];
  const float* Wfg = (const float*)d_in[15];
  const float* bfg = (const float*)d_in[16];
  const float* Embg= (const float*)d_in[17];
  const float* wg  = (const float*)d_in[18];

  int n = in_sizes[0] / 64;
  int E = in_sizes[2] / 2;

  char* base = (char*)d_ws;
  size_t off = 0;
  auto alloc = [&](size_t bytes) -> void* {
    void* p = base + off;
    off += bytes;
    off = (off + 255) & ~(size_t)255;
    return p;
  };
  unsigned* cntP   = (unsigned*)alloc((size_t)NREP * n * 4);
  int*   cursor    = (int*)alloc((size_t)n * 4);
  size_t zero_bytes = off;                 // cntP + cursor
  int*   deg_i     = (int*)alloc((size_t)n * 4);
  int*   row_start = (int*)alloc(((size_t)n + 1) * 4);
  int*   bsum      = (int*)alloc(1024 * 4);
  float* dinv      = (float*)alloc((size_t)n * 4);
  int2*  ec        = (int2*)alloc((size_t)E * 8);
  float* CFG       = (float*)alloc((size_t)n * 3 * 4);
  float* Wv4       = (float*)alloc((size_t)513 * 4 * 4);
  unsigned short* Wb = (unsigned short*)alloc((size_t)16 * 4 * 64 * 8 * 2);  // 64KB
  unsigned* Xu     = (unsigned*)alloc((size_t)n * 64 * 4);   // bf16 X: 128 feat x 2B
  unsigned* Ztu    = (unsigned*)alloc((size_t)n * 80 * 4);   // bf16 Zt (160 feat)
  (void)ws_size;

  hipMemsetAsync(base, 0, zero_bytes, stream);

  int nb_scan = (n + 1023) / 1024;
  k_degrees<<<(E + 255) / 256, 256, 0, stream>>>(ei, E, cntP, n);
  k_scan1<<<nb_scan, 1024, 0, stream>>>(cntP, n, bsum);
  k_scan2<<<1, 64, 0, stream>>>(bsum, nb_scan, row_start, n);
  k_scan3<<<nb_scan, 1024, 0, stream>>>(cntP, n, bsum, row_start, dinv, deg_i);
  k_wv<<<2, 256, 0, stream>>>(Wfg, bfg, wg, Wv4);
  k_wb<<<16, 256, 0, stream>>>(Wf0, Wf2, Wb);
  k_projm<<<(n + 15) / 16, 64, 0, stream>>>(feat, Wb, bf0, bf2, Wv4, Xu, CFG, n);
  k_buildx<<<((size_t)n * 32 + 255) / 256, 256, 0, stream>>>(logits, Xu, n);
  k_fill<<<(E + 255) / 256, 256, 0, stream>>>(ei, E, row_start, cursor, dinv, deg_i, ec);
  k_agg<<<(n + 3) / 4, 256, 0, stream>>>(Xu, Ztu, row_start, ec, deg_i, Emb1, Emb2, dinv, n);
  int waves = (n + 63) / 64;
  k_final<<<waves * 4, 64, 0, stream>>>(Ztu, logits, CFG, deg_i, W0, b0, W1, b1, W2, b2,
                                        Embg, wg, (float*)d_out, n);
}

// Round 16
// 497.902 us; speedup vs baseline: 1.2728x; 1.0369x over previous
//
#include <hip/hip_runtime.h>
#include <hip/hip_bf16.h>
#include <math.h>

// GETS calibrator: MoE-GCN. N nodes, E edges, C=64, F=512, FH=32, DH=16.
// R16: k_degrees + k_projm + k_buildx fused into k_combo (block-type partition,
//      interleaved). k_degrees is pinned at ~26 G atomics/s with 0.4% VALU --
//      overlap the idle CUs with the independent MFMA projection + logits pack.

#define XD 160   // aggregated feature dim (Zt layout)
#define CC 64    // classes
#define NREP 8   // counter replicas

typedef __attribute__((ext_vector_type(8))) short short8;
typedef __attribute__((ext_vector_type(4))) float f32x4;

static __device__ inline unsigned pk_bf16(float a, float b) {
  __hip_bfloat162 h;
  h.x = __float2bfloat16(a);
  h.y = __float2bfloat16(b);
  return *reinterpret_cast<unsigned*>(&h);
}
static __device__ inline unsigned short bf16u(float f) {
  __hip_bfloat16 h = __float2bfloat16(f);
  return *reinterpret_cast<unsigned short*>(&h);
}
static __device__ inline float bf_lo(unsigned u) {
  unsigned v = u << 16;
  return __builtin_bit_cast(float, v);
}
static __device__ inline float bf_hi(unsigned u) {
  unsigned v = u & 0xffff0000u;
  return __builtin_bit_cast(float, v);
}

// ---------------- k_combo: degree atomics (even blocks) + MFMA projection (odd) ----------
// Deg block idx: 1024 edges, 2 packed atomics each (indeg|outdeg<<16), NREP replicas.
// Proj block idx: 4 waves x 16 nodes; per wave: A-frag direct from feat, B from Wb,
// fused fp32 CFG (exact tree), logits->Xu bf16 pack (old k_buildx).
__global__ __launch_bounds__(256) void k_combo(
    const int* __restrict__ ei, int E,
    unsigned* __restrict__ cntP, int n,
    const float* __restrict__ feat, const unsigned short* __restrict__ Wb,
    const float* __restrict__ bf0, const float* __restrict__ bf2,
    const float* __restrict__ Wv4, const float* __restrict__ logits,
    unsigned* __restrict__ Xu, float* __restrict__ CFG,
    int nblk_deg, int nblk_proj) {
  int bid = blockIdx.x;
  int nmin2 = 2 * (nblk_deg < nblk_proj ? nblk_deg : nblk_proj);
  int type, idx;
  if (bid < nmin2) { type = bid & 1; idx = bid >> 1; }
  else {
    int r = bid - nmin2;
    if (nblk_deg > nblk_proj) { type = 0; idx = nblk_proj + r; }
    else                      { type = 1; idx = nblk_deg + r; }
  }

  if (type == 0) {
    // ---------- degree counting ----------
    int t = threadIdx.x;
    unsigned r = t & (NREP - 1);
    int base = idx * 1024;
#pragma unroll
    for (int q = 0; q < 4; ++q) {
      int e = base + q * 256 + t;
      if (e < E) {
        int s = ei[e], d = ei[E + e];
        atomicAdd(&cntP[r * (size_t)n + d], 1u);        // indeg
        atomicAdd(&cntP[r * (size_t)n + s], 0x10000u);  // outdeg
      }
    }
    return;
  }

  // ---------- projection (per-wave, identical math to R15 k_projm) ----------
  int l = threadIdx.x & 63;
  int wv = threadIdx.x >> 6;
  int gw = idx * 4 + wv;               // == old k_projm blockIdx
  int node_in = gw * 16 + (l & 15);
  int nc = node_in < n ? node_in : n - 1;
  const float* frow = feat + (size_t)nc * 512 + ((l >> 4) << 3);

  f32x4 acc[4];
#pragma unroll
  for (int q = 0; q < 4; ++q) acc[q] = (f32x4){0.f, 0.f, 0.f, 0.f};
  float cfg0 = 0.f, cfg1 = 0.f, cfg2 = 0.f;

  for (int ks = 0; ks < 16; ++ks) {
    float4 fa = *(const float4*)&frow[ks * 32];
    float4 fb = *(const float4*)&frow[ks * 32 + 4];
    float fv[8] = {fa.x, fa.y, fa.z, fa.w, fb.x, fb.y, fb.z, fb.w};
    const float* wvp = Wv4 + (ks * 32 + ((l >> 4) << 3)) * 4;
#pragma unroll
    for (int j = 0; j < 8; ++j) {
      float4 v = *(const float4*)&wvp[j * 4];
      cfg0 += fv[j] * v.x;
      cfg1 += fv[j] * v.y;
      cfg2 += fv[j] * v.z;
    }
    unsigned short pa[8];
#pragma unroll
    for (int j = 0; j < 8; ++j) pa[j] = bf16u(fv[j]);
    short8 af = *(const short8*)pa;
#pragma unroll
    for (int nt = 0; nt < 4; ++nt) {
      short8 bfv = *(const short8*)&Wb[(size_t)((ks * 4 + nt) * 64 + l) * 8];
      acc[nt] = __builtin_amdgcn_mfma_f32_16x16x32_bf16(af, bfv, acc[nt], 0, 0, 0);
    }
  }

  cfg0 += __shfl_xor(cfg0, 16); cfg0 += __shfl_xor(cfg0, 32);
  cfg1 += __shfl_xor(cfg1, 16); cfg1 += __shfl_xor(cfg1, 32);
  cfg2 += __shfl_xor(cfg2, 16); cfg2 += __shfl_xor(cfg2, 32);
  if (l < 16 && node_in < n) {
    float4 cc = *(const float4*)&Wv4[512 * 4];
    CFG[node_in] = cfg0 + cc.x;
    CFG[n + node_in] = cfg1 + cc.y;
    CFG[2 * (size_t)n + node_in] = cfg2 + cc.z;
  }

  unsigned short* Xus = (unsigned short*)Xu;
#pragma unroll
  for (int nt = 0; nt < 4; ++nt) {
    int col = (nt << 4) + (l & 15);
    float bias = (col < 32) ? bf0[col] : bf2[col - 32];
    int fidx = 64 + col;
#pragma unroll
    for (int r = 0; r < 4; ++r) {
      int nd = gw * 16 + ((l >> 4) << 2) + r;
      if (nd < n) Xus[(size_t)nd * 128 + fidx] = bf16u(acc[nt][r] + bias);
    }
  }

  // ---------- logits -> Xu bf16 pack (old k_buildx) for this wave's 16 nodes ----------
  int nb16 = gw * 16;
#pragma unroll
  for (int q = 0; q < 8; ++q) {
    int ii = q * 64 + l;               // 0..511
    int nd = nb16 + (ii >> 5);
    int p = ii & 31;
    if (nd < n) {
      float2 lg = *(const float2*)&logits[(size_t)nd * 64 + 2 * p];
      Xu[(size_t)nd * 64 + p] = pk_bf16(lg.x, lg.y);
    }
  }
}

// ---------------- 2-level exclusive scan of indeg -> row_start ----------------
__global__ void k_scan1(const unsigned* __restrict__ cntP, int n, int* __restrict__ bsum) {
  __shared__ int red[1024];
  int tid = threadIdx.x;
  int i = blockIdx.x * 1024 + tid;
  int v = 0;
  if (i < n) {
    unsigned t = 0;
#pragma unroll
    for (int r = 0; r < NREP; ++r) t += cntP[r * (size_t)n + i];
    v = (int)(t & 0xFFFFu);
  }
  red[tid] = v;
  __syncthreads();
  for (int s = 512; s > 0; s >>= 1) {
    if (tid < s) red[tid] += red[tid + s];
    __syncthreads();
  }
  if (tid == 0) bsum[blockIdx.x] = red[0];
}

__global__ void k_scan2(int* __restrict__ bsum, int nb, int* __restrict__ row_start, int n) {
  if (threadIdx.x == 0 && blockIdx.x == 0) {
    int run = 0;
    for (int b = 0; b < nb; ++b) { int t = bsum[b]; bsum[b] = run; run += t; }
    row_start[n] = run;   // == E
  }
}

__global__ void k_scan3(const unsigned* __restrict__ cntP, int n, const int* __restrict__ bsum,
                        int* __restrict__ row_start, float* __restrict__ dinv,
                        int* __restrict__ deg_i) {
  __shared__ int sc[1024];
  int tid = threadIdx.x;
  int i = blockIdx.x * 1024 + tid;
  int indeg = 0, total = 0;
  if (i < n) {
    unsigned t = 0;
#pragma unroll
    for (int r = 0; r < NREP; ++r) t += cntP[r * (size_t)n + i];
    indeg = (int)(t & 0xFFFFu);
    total = indeg + (int)(t >> 16);
  }
  sc[tid] = indeg;
  __syncthreads();
  for (int ofs = 1; ofs < 1024; ofs <<= 1) {
    int t = (tid >= ofs) ? sc[tid - ofs] : 0;
    __syncthreads();
    sc[tid] += t;
    __syncthreads();
  }
  if (i < n) {
    int incl = sc[tid];
    row_start[i] = incl - indeg + bsum[blockIdx.x];
    dinv[i] = rsqrtf((float)indeg + 1.0f);   // GCN deg = indeg + 1 (self loop)
    deg_i[i] = total;                        // embedding degree = indeg + outdeg
  }
}

// ---------------- CSR fill: (src | deg<<20, coef) per edge ----------------
__global__ void k_fill(const int* __restrict__ ei, int E, const int* __restrict__ row_start,
                       int* __restrict__ cursor, const float* __restrict__ dinv,
                       const int* __restrict__ deg_i, int2* __restrict__ ec) {
  int e = blockIdx.x * blockDim.x + threadIdx.x;
  if (e >= E) return;
  int s = ei[e], d = ei[E + e];
  int pos = row_start[d] + atomicAdd(&cursor[d], 1);
  int dg = deg_i[s]; if (dg > 127) dg = 127;
  int2 v;
  v.x = s | (dg << 20);
  v.y = __float_as_int(dinv[s] * dinv[d]);
  ec[pos] = v;
}

// ---------------- Wv = Wfg(512x32) @ wg[64:96] (3 cols), fp32 ----------------
__global__ void k_wv(const float* __restrict__ Wfg, const float* __restrict__ bfg,
                     const float* __restrict__ wg, float* __restrict__ Wv4) {
  int k = blockIdx.x * blockDim.x + threadIdx.x;
  if (k >= 512) return;
  float a0 = 0.f, a1 = 0.f, a2 = 0.f;
  for (int j = 0; j < 32; ++j) {
    float w = Wfg[k * 32 + j];
    a0 += w * wg[(64 + j) * 3 + 0];
    a1 += w * wg[(64 + j) * 3 + 1];
    a2 += w * wg[(64 + j) * 3 + 2];
  }
  float4 v; v.x = a0; v.y = a1; v.z = a2; v.w = 0.f;
  *(float4*)&Wv4[k * 4] = v;
  if (k == 0) {
    float c0 = 0.f, c1 = 0.f, c2 = 0.f;
    for (int j = 0; j < 32; ++j) {
      float b = bfg[j];
      c0 += b * wg[(64 + j) * 3 + 0];
      c1 += b * wg[(64 + j) * 3 + 1];
      c2 += b * wg[(64 + j) * 3 + 2];
    }
    float4 c; c.x = c0; c.y = c1; c.z = c2; c.w = 0.f;
    *(float4*)&Wv4[512 * 4] = c;
  }
}

// ---------------- k_wb: [Wf0|Wf2] -> bf16 fragment-ordered Wb ----------------
__global__ void k_wb(const float* __restrict__ Wf0, const float* __restrict__ Wf2,
                     unsigned short* __restrict__ Wb) {
  int tid = blockIdx.x * blockDim.x + threadIdx.x;   // 4096 threads
  if (tid >= 16 * 4 * 64) return;
  int l = tid & 63;
  int nt = (tid >> 6) & 3;
  int ks = tid >> 8;
  int col = (nt << 4) + (l & 15);
  int rowb = ks * 32 + ((l >> 4) << 3);
  const float* wsrc = (col < 32) ? (Wf0 + col) : (Wf2 + (col - 32));
  unsigned short pb[8];
#pragma unroll
  for (int j = 0; j < 8; ++j)
    pb[j] = bf16u(wsrc[(size_t)(rowb + j) * 32]);
  *(uint4*)&Wb[(size_t)tid * 8] = *(const uint4*)pb;
}

// ---------------- aggregation: Zt(bf16) = A_hat @ [Xu(256B rows) | Emb(packed deg)] ------
__global__ __launch_bounds__(256) void k_agg(
    const unsigned* __restrict__ Xu, unsigned* __restrict__ Ztu,
    const int* __restrict__ row_start, const int2* __restrict__ ec,
    const int* __restrict__ deg_i,
    const float* __restrict__ Emb1, const float* __restrict__ Emb2,
    const float* __restrict__ dinv, int n) {
  int w = threadIdx.x >> 6, l = threadIdx.x & 63;
  int node = blockIdx.x * 4 + w;
  if (node >= n) return;
  int beg = row_start[node], end = row_start[node + 1];

  const float* etab = (l < 8) ? (Emb1 + 2 * l) : (Emb2 + 2 * (l - 8));

  float ax = 0.f, ay = 0.f, bx = 0.f, by = 0.f;
  int i = beg;
  for (; i + 4 <= end; i += 4) {
    int2 e0 = ec[i];
    int2 e1 = ec[i + 1];
    int2 e2 = ec[i + 2];
    int2 e3 = ec[i + 3];
    unsigned u0 = Xu[(size_t)(e0.x & 0xFFFFF) * 64 + l];
    unsigned u1 = Xu[(size_t)(e1.x & 0xFFFFF) * 64 + l];
    unsigned u2 = Xu[(size_t)(e2.x & 0xFFFFF) * 64 + l];
    unsigned u3 = Xu[(size_t)(e3.x & 0xFFFFF) * 64 + l];
    float c0 = __int_as_float(e0.y);
    float c1 = __int_as_float(e1.y);
    float c2 = __int_as_float(e2.y);
    float c3 = __int_as_float(e3.y);
    ax += c0 * bf_lo(u0); ay += c0 * bf_hi(u0);
    ax += c1 * bf_lo(u1); ay += c1 * bf_hi(u1);
    ax += c2 * bf_lo(u2); ay += c2 * bf_hi(u2);
    ax += c3 * bf_lo(u3); ay += c3 * bf_hi(u3);
    if (l < 16) {
      float2 ev0 = *(const float2*)&etab[(e0.x >> 20) * 16];
      float2 ev1 = *(const float2*)&etab[(e1.x >> 20) * 16];
      float2 ev2 = *(const float2*)&etab[(e2.x >> 20) * 16];
      float2 ev3 = *(const float2*)&etab[(e3.x >> 20) * 16];
      bx += c0 * ev0.x; by += c0 * ev0.y;
      bx += c1 * ev1.x; by += c1 * ev1.y;
      bx += c2 * ev2.x; by += c2 * ev2.y;
      bx += c3 * ev3.x; by += c3 * ev3.y;
    }
  }
  for (; i < end; ++i) {
    int2 e0 = ec[i];
    int s0 = e0.x & 0xFFFFF;
    float c0 = __int_as_float(e0.y);
    unsigned u0 = Xu[(size_t)s0 * 64 + l];
    ax += c0 * bf_lo(u0); ay += c0 * bf_hi(u0);
    if (l < 16) {
      float2 ev0 = *(const float2*)&etab[(e0.x >> 20) * 16];
      bx += c0 * ev0.x; by += c0 * ev0.y;
    }
  }
  // self loop
  float di = dinv[node];
  float c2s = di * di;
  {
    unsigned u = Xu[(size_t)node * 64 + l];
    ax += c2s * bf_lo(u);
    ay += c2s * bf_hi(u);
    if (l < 16) {
      int dg = deg_i[node]; if (dg > 127) dg = 127;
      float2 ev = *(const float2*)&etab[dg * 16];
      bx += c2s * ev.x;
      by += c2s * ev.y;
    }
  }
  // main store: new feature nf=2l -> old feature (nf<96 ? nf : nf+16)
  {
    int nf = 2 * l;
    int of = nf + (nf >= 96 ? 16 : 0);
    Ztu[2 * ((size_t)(of >> 2) * n + node) + ((of >> 1) & 1)] = pk_bf16(ax, ay);
  }
  if (l < 16) {
    int p = l & 7;
    int of = (l < 8) ? (96 + 2 * p) : (144 + 2 * p);
    Ztu[2 * ((size_t)(of >> 2) * n + node) + (p & 1)] = pk_bf16(bx, by);
  }
}

// ---------------- final: 4-way column split, 1 wave/block, comb[16] ----------------
__global__ __launch_bounds__(64) void k_final(
    const unsigned* __restrict__ Ztu, const float* __restrict__ logits,
    const float* __restrict__ CFG, const int* __restrict__ deg_i,
    const float* __restrict__ W0, const float* __restrict__ b0,
    const float* __restrict__ W1, const float* __restrict__ b1,
    const float* __restrict__ W2, const float* __restrict__ b2,
    const float* __restrict__ Embg, const float* __restrict__ wg,
    float* __restrict__ out, int n) {
  int l = threadIdx.x;
  int g = blockIdx.x >> 2;
  int cb = (blockIdx.x & 3) * 16;      // column base
  int node = g * 64 + l;
  int nc = node < n ? node : n - 1;

  // ---- gating (fp32, full; identical in all 4 col-groups) ----
  float c0 = 0.f, c1 = 0.f, c2 = 0.f;
  const float* lgr = logits + (size_t)nc * 64;
#pragma unroll
  for (int q = 0; q < 16; ++q) {
    float4 v = *(const float4*)&lgr[q * 4];
    const float* p = (const float*)&v;
#pragma unroll
    for (int j = 0; j < 4; ++j) {
      int k = q * 4 + j;
      c0 += p[j] * wg[k * 3 + 0];
      c1 += p[j] * wg[k * 3 + 1];
      c2 += p[j] * wg[k * 3 + 2];
    }
  }
  {
    int dg = deg_i[nc]; if (dg > 127) dg = 127;
    const float* egr = Embg + dg * 16;
#pragma unroll
    for (int q = 0; q < 4; ++q) {
      float4 v = *(const float4*)&egr[q * 4];
      const float* p = (const float*)&v;
#pragma unroll
      for (int j = 0; j < 4; ++j) {
        int k = 96 + q * 4 + j;
        c0 += p[j] * wg[k * 3 + 0];
        c1 += p[j] * wg[k * 3 + 1];
        c2 += p[j] * wg[k * 3 + 2];
      }
    }
  }
  c0 += CFG[nc];
  c1 += CFG[n + nc];
  c2 += CFG[2 * (size_t)n + nc];

  int i0 = 0; float t0 = c0;
  if (c1 > t0) { t0 = c1; i0 = 1; }
  if (c2 > t0) { t0 = c2; i0 = 2; }
  float t1 = -3.4e38f; int i1 = 0;
  if (i0 != 0) { t1 = c0; i1 = 0; }
  if (i0 != 1 && c1 > t1) { t1 = c1; i1 = 1; }
  if (i0 != 2 && c2 > t1) { t1 = c2; i1 = 2; }
  float e1v = expf(t1 - t0);
  float gsum = 1.0f + e1v;
  float gA = 1.0f / gsum, gB = e1v / gsum;
  float g0 = (i0 == 0) ? gA : (i1 == 0) ? gB : 0.f;
  float g1 = (i0 == 1) ? gA : (i1 == 1) ? gB : 0.f;
  float g2 = (i0 == 2) ? gA : (i1 == 2) ? gB : 0.f;

  float comb[16];
#pragma unroll
  for (int c = 0; c < 16; ++c) comb[c] = 0.f;

#define CHUNK(CIDX, GE, WPTR, KROW)                                        \
  {                                                                        \
    uint2 zu = *(const uint2*)&Ztu[2 * ((size_t)(CIDX) * n + nc)];         \
    float zs[4] = {(GE) * bf_lo(zu.x), (GE) * bf_hi(zu.x),                 \
                   (GE) * bf_lo(zu.y), (GE) * bf_hi(zu.y)};                \
    const float* wr = (WPTR) + (KROW) * 64 + cb;                           \
    _Pragma("unroll") for (int kk = 0; kk < 4; ++kk) {                     \
      float zz = zs[kk];                                                   \
      const float* wrow = wr + kk * 64;                                    \
      _Pragma("unroll") for (int c = 0; c < 16; ++c)                       \
        comb[c] += zz * wrow[c];                                           \
    }                                                                      \
  }

  for (int t = 0; t < 24; ++t) CHUNK(t, g0, W0, 4 * t);
  for (int t = 0; t < 16; ++t) CHUNK(t, g1, W1, 4 * t);
  for (int t = 0; t < 4; ++t)  CHUNK(24 + t, g1, W1, 64 + 4 * t);
  for (int t = 0; t < 12; ++t) CHUNK(28 + t, g2, W2, 4 * t);
#undef CHUNK

#pragma unroll
  for (int c = 0; c < 16; ++c)
    comb[c] += g0 * b0[cb + c] + g1 * b1[cb + c] + g2 * b2[cb + c];

  if (node < n) {
    float* outr = out + (size_t)node * 64 + cb;
#pragma unroll
    for (int q = 0; q < 4; ++q) {
      float4 lg4 = *(const float4*)&lgr[cb + q * 4];
      const float* pl = (const float*)&lg4;
      float4 o;
      float* po = (float*)&o;
#pragma unroll
      for (int j = 0; j < 4; ++j) {
        float v = comb[q * 4 + j];
        float sp = fmaxf(v, 0.f) + log1pf(expf(-fabsf(v)));
        po[j] = pl[j] * sp;
      }
      *(float4*)&outr[q * 4] = o;
    }
  }
}

extern "C" void kernel_launch(void* const* d_in, const int* in_sizes, int n_in,
                              void* d_out, int out_size, void* d_ws, size_t ws_size,
                              hipStream_t stream) {
  const float* logits = (const float*)d_in[0];
  const float* feat   = (const float*)d_in[1];
  const int*   ei     = (const int*)d_in[2];
  const float* Wf0 = (const float*)d_in[3];
  const float* bf0 = (const float*)d_in[4];
  const float* W0  = (const float*)d_in[5];
  const float* b0  = (const float*)d_in[6];
  const float* Emb1= (const float*)d_in[7];
  const float* W1  = (const float*)d_in[8];
  const float* b1  = (const float*)d_in[9];
  const float* Wf2 = (const float*)d_in[10];
  const float* bf2 = (const float*)d_in[11];
  const float* Emb2= (const float*)d_in[12];
  const float* W2  = (const float*)d_in[13];
  const float* b2  = (const float*)d_in[14];
  const float* Wfg = (const float*)d_in[15];
  const float* bfg = (const float*)d_in[16];
  const float* Embg= (const float*)d_in[17];
  const float* wg  = (const float*)d_in[18];

  int n = in_sizes[0] / 64;
  int E = in_sizes[2] / 2;

  char* base = (char*)d_ws;
  size_t off = 0;
  auto alloc = [&](size_t bytes) -> void* {
    void* p = base + off;
    off += bytes;
    off = (off + 255) & ~(size_t)255;
    return p;
  };
  unsigned* cntP   = (unsigned*)alloc((size_t)NREP * n * 4);
  int*   cursor    = (int*)alloc((size_t)n * 4);
  size_t zero_bytes = off;                 // cntP + cursor
  int*   deg_i     = (int*)alloc((size_t)n * 4);
  int*   row_start = (int*)alloc(((size_t)n + 1) * 4);
  int*   bsum      = (int*)alloc(1024 * 4);
  float* dinv      = (float*)alloc((size_t)n * 4);
  int2*  ec        = (int2*)alloc((size_t)E * 8);
  float* CFG       = (float*)alloc((size_t)n * 3 * 4);
  float* Wv4       = (float*)alloc((size_t)513 * 4 * 4);
  unsigned short* Wb = (unsigned short*)alloc((size_t)16 * 4 * 64 * 8 * 2);  // 64KB
  unsigned* Xu     = (unsigned*)alloc((size_t)n * 64 * 4);   // bf16 X: 128 feat x 2B
  unsigned* Ztu    = (unsigned*)alloc((size_t)n * 80 * 4);   // bf16 Zt (160 feat)
  (void)ws_size;

  hipMemsetAsync(base, 0, zero_bytes, stream);

  int nb_scan = (n + 1023) / 1024;
  int nblk_deg  = (E + 1023) / 1024;
  int nblk_proj = (n + 63) / 64;
  k_wv<<<2, 256, 0, stream>>>(Wfg, bfg, wg, Wv4);
  k_wb<<<16, 256, 0, stream>>>(Wf0, Wf2, Wb);
  k_combo<<<nblk_deg + nblk_proj, 256, 0, stream>>>(
      ei, E, cntP, n, feat, Wb, bf0, bf2, Wv4, logits, Xu, CFG,
      nblk_deg, nblk_proj);
  k_scan1<<<nb_scan, 1024, 0, stream>>>(cntP, n, bsum);
  k_scan2<<<1, 64, 0, stream>>>(bsum, nb_scan, row_start, n);
  k_scan3<<<nb_scan, 1024, 0, stream>>>(cntP, n, bsum, row_start, dinv, deg_i);
  k_fill<<<(E + 255) / 256, 256, 0, stream>>>(ei, E, row_start, cursor, dinv, deg_i, ec);
  k_agg<<<(n + 3) / 4, 256, 0, stream>>>(Xu, Ztu, row_start, ec, deg_i, Emb1, Emb2, dinv, n);
  int waves = (n + 63) / 64;
  k_final<<<waves * 4, 64, 0, stream>>>(Ztu, logits, CFG, deg_i, W0, b0, W1, b1, W2, b2,
                                        Embg, wg, (float*)d_out, n);
}